// Round 2
// baseline (2894.581 us; speedup 1.0000x reference)
//
#include <hip/hip_runtime.h>

#define N_NODES 100000
#define EDGES   1600000
#define H 64

// ---------- input projection: out = relu(x @ W^T + b); x:[N,D] f32, W:[64,D] f32 ----------
// K-tiled so LDS stays small. 16 rows per block, 256 threads (4 waves x 4 rows each).
template<int D, int KT>
__global__ __launch_bounds__(256) void proj_relu(
    const float* __restrict__ x, const float* __restrict__ w,
    const float* __restrict__ b, float* __restrict__ out)
{
    __shared__ float Wt[KT * 64];   // Wt[kk*64+j] = w[j*D + k0+kk]
    __shared__ float Xs[16 * KT];
    const int tid  = threadIdx.x;
    const int base = blockIdx.x * 16;
    const int j  = tid & 63;
    const int r0 = (tid >> 6) * 4;
    float a0 = 0.f, a1 = 0.f, a2 = 0.f, a3 = 0.f;

    for (int k0 = 0; k0 < D; k0 += KT) {
        for (int idx = tid; idx < KT * 64; idx += 256) {
            int jj = idx / KT;              // const divisor -> magic mul
            int kk = idx - jj * KT;
            Wt[kk * 64 + jj] = w[(size_t)jj * D + k0 + kk];
        }
        for (int r = 0; r < 16; ++r) {
            const float* xr = x + (size_t)(base + r) * D + k0;
            for (int kk = tid; kk < KT; kk += 256) Xs[r * KT + kk] = xr[kk];
        }
        __syncthreads();
        for (int kk = 0; kk < KT; ++kk) {
            float wv = Wt[kk * 64 + j];               // lanes j contiguous: conflict-free
            a0 += Xs[(r0 + 0) * KT + kk] * wv;        // broadcast within wave
            a1 += Xs[(r0 + 1) * KT + kk] * wv;
            a2 += Xs[(r0 + 2) * KT + kk] * wv;
            a3 += Xs[(r0 + 3) * KT + kk] * wv;
        }
        __syncthreads();
    }
    float bv = b[j];
    out[(size_t)(base + r0 + 0) * H + j] = fmaxf(a0 + bv, 0.f);
    out[(size_t)(base + r0 + 1) * H + j] = fmaxf(a1 + bv, 0.f);
    out[(size_t)(base + r0 + 2) * H + j] = fmaxf(a2 + bv, 0.f);
    out[(size_t)(base + r0 + 3) * H + j] = fmaxf(a3 + bv, 0.f);
}

// ---------- per-dst-node in-degree ----------
__global__ __launch_bounds__(256) void count_edges(
    const int* __restrict__ ei, float* __restrict__ cnt)
{
    int e = blockIdx.x * 256 + threadIdx.x;
    if (e < EDGES) atomicAdd(&cnt[ei[EDGES + e]], 1.0f);
}

// ---------- scatter-add src features along edges: wave per edge, lane per feature ----------
__global__ __launch_bounds__(256) void scatter_feats(
    const float* __restrict__ src_feat, const int* __restrict__ ei,
    float* __restrict__ agg)
{
    long t = (long)blockIdx.x * 256 + threadIdx.x;
    int e = (int)(t >> 6);
    int f = (int)(t & 63);
    if (e < EDGES) {
        int s = ei[e];
        int d = ei[EDGES + e];
        atomicAdd(&agg[(size_t)d * H + f], src_feat[(size_t)s * H + f]);
    }
}

// ---------- SAGE node update: out = [relu]( (agg/cnt) @ Wl^T + bl + xdst @ Wr^T ) ----------
// HEAD fuses the OUT=2 head. Safe to run in-place (out == xdst): row-local.
template<bool RELU, bool HEAD>
__global__ __launch_bounds__(256) void sage_node(
    const float* __restrict__ agg, const float* __restrict__ cnt,
    const float* __restrict__ xdst,
    const float* __restrict__ wl, const float* __restrict__ bl,
    const float* __restrict__ wr,
    float* __restrict__ out,
    const float* __restrict__ wout, const float* __restrict__ bout,
    float* __restrict__ out_head)
{
    __shared__ float Wlt[64 * 64], Wrt[64 * 64];   // transposed
    __shared__ float Ms[4 * 64], Xs[4 * 64];
    __shared__ float A2[HEAD ? 4 * 64 : 1];

    const int tid = threadIdx.x;
    for (int idx = tid; idx < 4096; idx += 256) {
        int jj = idx >> 6, kk = idx & 63;
        Wlt[kk * 64 + jj] = wl[idx];
        Wrt[kk * 64 + jj] = wr[idx];
    }
    const int r = tid >> 6, j = tid & 63;
    const int row = blockIdx.x * 4 + r;
    float inv = 1.0f / fmaxf(cnt[row], 1.0f);
    Ms[r * 64 + j] = agg[(size_t)row * H + j] * inv;
    Xs[r * 64 + j] = xdst[(size_t)row * H + j];
    __syncthreads();

    float acc = bl[j];
    for (int k = 0; k < 64; ++k) {
        acc += Ms[r * 64 + k] * Wlt[k * 64 + j];
        acc += Xs[r * 64 + k] * Wrt[k * 64 + j];
    }
    if (RELU) acc = fmaxf(acc, 0.f);

    if (!HEAD) {
        out[(size_t)row * H + j] = acc;
    } else {
        A2[r * 64 + j] = acc;
        __syncthreads();
        if (j < 2) {
            float o = bout[j];
            for (int k = 0; k < 64; ++k)
                o += A2[r * 64 + k] * wout[j * 64 + k];
            out_head[(size_t)row * 2 + j] = o;
        }
    }
}

extern "C" void kernel_launch(void* const* d_in, const int* in_sizes, int n_in,
                              void* d_out, int out_size, void* d_ws, size_t ws_size,
                              hipStream_t stream) {
    const float* x_a    = (const float*)d_in[0];
    const float* x_u    = (const float*)d_in[1];
    const int*   ei_p   = (const int*)d_in[2];
    const int*   ei_b   = (const int*)d_in[3];
    const float* w_in_a = (const float*)d_in[4];
    const float* b_in_a = (const float*)d_in[5];
    const float* w_in_u = (const float*)d_in[6];
    const float* b_in_u = (const float*)d_in[7];
    const float* c1p_wl = (const float*)d_in[8];
    const float* c1p_bl = (const float*)d_in[9];
    const float* c1p_wr = (const float*)d_in[10];
    const float* c1b_wl = (const float*)d_in[11];
    const float* c1b_bl = (const float*)d_in[12];
    const float* c1b_wr = (const float*)d_in[13];
    const float* c2p_wl = (const float*)d_in[14];
    const float* c2p_bl = (const float*)d_in[15];
    const float* c2p_wr = (const float*)d_in[16];
    const float* w_out  = (const float*)d_in[20];
    const float* b_out  = (const float*)d_in[21];

    const size_t NF = (size_t)N_NODES * H;   // 6.4M floats
    float* bufA  = (float*)d_ws;             // a, then a1 (in-place)
    float* bufU  = bufA  + NF;               // u, then u1 (in-place)
    float* aggP  = bufU  + NF;               // agg over ei_posts (reused for conv2)
    float* aggB  = aggP  + NF;               // agg over ei_pb
    float* cnt_p = aggB  + NF;
    float* cnt_b = cnt_p + N_NODES;          // total 103.2 MB

    const dim3 blk(256);
    const int grid_proj = N_NODES / 16;      // 6250
    const int grid_node = N_NODES / 4;       // 25000
    const int grid_cnt  = EDGES / 256;       // 6250
    const int grid_scat = EDGES * H / 256;   // 400000

    // degree counts (reused across layers)
    hipMemsetAsync(cnt_p, 0, 2 * N_NODES * sizeof(float), stream);
    count_edges<<<grid_cnt, blk, 0, stream>>>(ei_p, cnt_p);
    count_edges<<<grid_cnt, blk, 0, stream>>>(ei_b, cnt_b);

    // input projections
    proj_relu<300, 100><<<grid_proj, blk, 0, stream>>>(x_a, w_in_a, b_in_a, bufA);
    proj_relu<64, 64>  <<<grid_proj, blk, 0, stream>>>(x_u, w_in_u, b_in_u, bufU);

    // conv1 aggregations (both BEFORE the in-place node updates)
    hipMemsetAsync(aggP, 0, 2 * NF * sizeof(float), stream);   // zero aggP + aggB
    scatter_feats<<<grid_scat, blk, 0, stream>>>(bufU, ei_p, aggP);  // users -> articles
    scatter_feats<<<grid_scat, blk, 0, stream>>>(bufA, ei_b, aggB);  // articles -> users

    // conv1 node updates (in-place: a->a1, u->u1)
    sage_node<true, false><<<grid_node, blk, 0, stream>>>(
        aggP, cnt_p, bufA, c1p_wl, c1p_bl, c1p_wr, bufA, nullptr, nullptr, nullptr);
    sage_node<true, false><<<grid_node, blk, 0, stream>>>(
        aggB, cnt_b, bufU, c1b_wl, c1b_bl, c1b_wr, bufU, nullptr, nullptr, nullptr);

    // conv2 article side + fused output head
    hipMemsetAsync(aggP, 0, NF * sizeof(float), stream);
    scatter_feats<<<grid_scat, blk, 0, stream>>>(bufU, ei_p, aggP);  // u1 -> articles
    sage_node<false, true><<<grid_node, blk, 0, stream>>>(
        aggP, cnt_p, bufA, c2p_wl, c2p_bl, c2p_wr, nullptr, w_out, b_out,
        (float*)d_out);

    (void)in_sizes; (void)n_in; (void)out_size; (void)ws_size;
}

// Round 3
// 1820.541 us; speedup vs baseline: 1.5900x; 1.5900x over previous
//
#include <hip/hip_runtime.h>

#define N_NODES 100000
#define EDGES   1600000
#define H 64
#define ROWS 32   // rows per sage_node block

// ---------- input projection: out = relu(x @ W^T + b); x:[N,D] f32, W:[64,D] f32 ----------
template<int D, int KT>
__global__ __launch_bounds__(256) void proj_relu(
    const float* __restrict__ x, const float* __restrict__ w,
    const float* __restrict__ b, float* __restrict__ out)
{
    __shared__ float Wt[KT * 64];   // Wt[kk*64+j] = w[j*D + k0+kk]
    __shared__ float Xs[16 * KT];
    const int tid  = threadIdx.x;
    const int base = blockIdx.x * 16;
    const int j  = tid & 63;
    const int r0 = (tid >> 6) * 4;
    float a0 = 0.f, a1 = 0.f, a2 = 0.f, a3 = 0.f;

    for (int k0 = 0; k0 < D; k0 += KT) {
        for (int idx = tid; idx < KT * 64; idx += 256) {
            int jj = idx / KT;              // const divisor -> magic mul
            int kk = idx - jj * KT;
            Wt[kk * 64 + jj] = w[(size_t)jj * D + k0 + kk];
        }
        for (int r = 0; r < 16; ++r) {
            const float* xr = x + (size_t)(base + r) * D + k0;
            for (int kk = tid; kk < KT; kk += 256) Xs[r * KT + kk] = xr[kk];
        }
        __syncthreads();
        for (int kk = 0; kk < KT; ++kk) {
            float wv = Wt[kk * 64 + j];
            a0 += Xs[(r0 + 0) * KT + kk] * wv;
            a1 += Xs[(r0 + 1) * KT + kk] * wv;
            a2 += Xs[(r0 + 2) * KT + kk] * wv;
            a3 += Xs[(r0 + 3) * KT + kk] * wv;
        }
        __syncthreads();
    }
    float bv = b[j];
    out[(size_t)(base + r0 + 0) * H + j] = fmaxf(a0 + bv, 0.f);
    out[(size_t)(base + r0 + 1) * H + j] = fmaxf(a1 + bv, 0.f);
    out[(size_t)(base + r0 + 2) * H + j] = fmaxf(a2 + bv, 0.f);
    out[(size_t)(base + r0 + 3) * H + j] = fmaxf(a3 + bv, 0.f);
}

// ---------- per-dst-node in-degree ----------
__global__ __launch_bounds__(256) void count_edges(
    const int* __restrict__ ei, float* __restrict__ cnt)
{
    int e = blockIdx.x * 256 + threadIdx.x;
    if (e < EDGES) atomicAdd(&cnt[ei[EDGES + e]], 1.0f);
}

// ---------- scatter-add src features along edges: wave per edge, lane per feature ----------
__global__ __launch_bounds__(256) void scatter_feats(
    const float* __restrict__ src_feat, const int* __restrict__ ei,
    float* __restrict__ agg)
{
    long t = (long)blockIdx.x * 256 + threadIdx.x;
    int e = (int)(t >> 6);
    int f = (int)(t & 63);
    if (e < EDGES) {
        int s = ei[e];
        int d = ei[EDGES + e];
        atomicAdd(&agg[(size_t)d * H + f], src_feat[(size_t)s * H + f]);
    }
}

// ---------- SAGE node update: out = [relu]( (agg/cnt) @ Wl^T + bl + xdst @ Wr^T ) ----------
// ROWS rows/block, 256 threads: each thread computes 8 rows x 1 feature.
// Weights staged transposed with rotate swizzle (k*64 + (j+k)&63): conflict-free
// writes AND reads. Ms/Xs row-major: float4 wave-broadcast reads (no conflict).
// Safe in-place (out == xdst): row-local.
template<bool RELU, bool HEAD>
__global__ __launch_bounds__(256) void sage_node(
    const float* __restrict__ agg, const float* __restrict__ cnt,
    const float* __restrict__ xdst,
    const float* __restrict__ wl, const float* __restrict__ bl,
    const float* __restrict__ wr,
    float* __restrict__ out,
    const float* __restrict__ wout, const float* __restrict__ bout,
    float* __restrict__ out_head)
{
    __shared__ float Wlt[64 * 64], Wrt[64 * 64];   // rotate-swizzled transpose
    __shared__ float Ms[ROWS * 64], Xs[ROWS * 64]; // row-major (also reused as A2 for HEAD)
    __shared__ float invS[ROWS];

    const int tid  = threadIdx.x;
    const int base = blockIdx.x * ROWS;

    if (tid < ROWS) invS[tid] = 1.0f / fmaxf(cnt[base + tid], 1.0f);
    // weights: global read linear/coalesced; LDS write swizzled, conflict-free
    for (int idx = tid; idx < 4096; idx += 256) {
        int jj = idx >> 6, kk = idx & 63;
        int js = (jj + kk) & 63;
        Wlt[kk * 64 + js] = wl[idx];
        Wrt[kk * 64 + js] = wr[idx];
    }
    __syncthreads();
    for (int i = tid; i < ROWS * 64; i += 256) {
        int r = i >> 6, jj = i & 63;
        Ms[i] = agg[(size_t)(base + r) * H + jj] * invS[r];
        Xs[i] = xdst[(size_t)(base + r) * H + jj];
    }
    __syncthreads();

    const int j  = tid & 63;
    const int r0 = (tid >> 6) * 8;
    float acc[8];
    {
        const float bv = bl[j];
        #pragma unroll
        for (int i = 0; i < 8; ++i) acc[i] = bv;
    }
    for (int k0 = 0; k0 < 64; k0 += 4) {
        float wlv[4], wrv[4];
        #pragma unroll
        for (int kk = 0; kk < 4; ++kk) {
            const int k = k0 + kk;
            const int js = (j + k) & 63;
            wlv[kk] = Wlt[k * 64 + js];
            wrv[kk] = Wrt[k * 64 + js];
        }
        #pragma unroll
        for (int i = 0; i < 8; ++i) {
            const float4 mv = *(const float4*)&Ms[(r0 + i) * 64 + k0];
            const float4 xv = *(const float4*)&Xs[(r0 + i) * 64 + k0];
            acc[i] += mv.x * wlv[0] + mv.y * wlv[1] + mv.z * wlv[2] + mv.w * wlv[3];
            acc[i] += xv.x * wrv[0] + xv.y * wrv[1] + xv.z * wrv[2] + xv.w * wrv[3];
        }
    }

    if (!HEAD) {
        #pragma unroll
        for (int i = 0; i < 8; ++i) {
            float v = RELU ? fmaxf(acc[i], 0.f) : acc[i];
            out[(size_t)(base + r0 + i) * H + j] = v;
        }
    } else {
        __syncthreads();                       // done reading Ms
        #pragma unroll
        for (int i = 0; i < 8; ++i)
            Ms[(r0 + i) * 64 + j] = acc[i];    // reuse Ms as A2
        __syncthreads();
        if (tid < 2 * ROWS) {
            const int r = tid >> 1, o = tid & 1;
            float v = bout[o];
            for (int k = 0; k < 64; ++k)
                v += Ms[r * 64 + k] * wout[o * 64 + k];
            out_head[(size_t)(base + r) * 2 + o] = v;
        }
    }
}

extern "C" void kernel_launch(void* const* d_in, const int* in_sizes, int n_in,
                              void* d_out, int out_size, void* d_ws, size_t ws_size,
                              hipStream_t stream) {
    const float* x_a    = (const float*)d_in[0];
    const float* x_u    = (const float*)d_in[1];
    const int*   ei_p   = (const int*)d_in[2];
    const int*   ei_b   = (const int*)d_in[3];
    const float* w_in_a = (const float*)d_in[4];
    const float* b_in_a = (const float*)d_in[5];
    const float* w_in_u = (const float*)d_in[6];
    const float* b_in_u = (const float*)d_in[7];
    const float* c1p_wl = (const float*)d_in[8];
    const float* c1p_bl = (const float*)d_in[9];
    const float* c1p_wr = (const float*)d_in[10];
    const float* c1b_wl = (const float*)d_in[11];
    const float* c1b_bl = (const float*)d_in[12];
    const float* c1b_wr = (const float*)d_in[13];
    const float* c2p_wl = (const float*)d_in[14];
    const float* c2p_bl = (const float*)d_in[15];
    const float* c2p_wr = (const float*)d_in[16];
    const float* w_out  = (const float*)d_in[20];
    const float* b_out  = (const float*)d_in[21];

    const size_t NF = (size_t)N_NODES * H;   // 6.4M floats
    float* bufA  = (float*)d_ws;             // a, then a1 (in-place)
    float* bufU  = bufA  + NF;               // u, then u1 (in-place)
    float* aggP  = bufU  + NF;
    float* aggB  = aggP  + NF;
    float* cnt_p = aggB  + NF;
    float* cnt_b = cnt_p + N_NODES;

    const dim3 blk(256);
    const int grid_proj = N_NODES / 16;        // 6250
    const int grid_node = N_NODES / ROWS;      // 3125
    const int grid_cnt  = EDGES / 256;         // 6250
    const int grid_scat = EDGES * H / 256;     // 400000

    hipMemsetAsync(cnt_p, 0, 2 * N_NODES * sizeof(float), stream);
    count_edges<<<grid_cnt, blk, 0, stream>>>(ei_p, cnt_p);
    count_edges<<<grid_cnt, blk, 0, stream>>>(ei_b, cnt_b);

    proj_relu<300, 100><<<grid_proj, blk, 0, stream>>>(x_a, w_in_a, b_in_a, bufA);
    proj_relu<64, 64>  <<<grid_proj, blk, 0, stream>>>(x_u, w_in_u, b_in_u, bufU);

    hipMemsetAsync(aggP, 0, 2 * NF * sizeof(float), stream);
    scatter_feats<<<grid_scat, blk, 0, stream>>>(bufU, ei_p, aggP);  // users -> articles
    scatter_feats<<<grid_scat, blk, 0, stream>>>(bufA, ei_b, aggB);  // articles -> users

    sage_node<true, false><<<grid_node, blk, 0, stream>>>(
        aggP, cnt_p, bufA, c1p_wl, c1p_bl, c1p_wr, bufA, nullptr, nullptr, nullptr);
    sage_node<true, false><<<grid_node, blk, 0, stream>>>(
        aggB, cnt_b, bufU, c1b_wl, c1b_bl, c1b_wr, bufU, nullptr, nullptr, nullptr);

    hipMemsetAsync(aggP, 0, NF * sizeof(float), stream);
    scatter_feats<<<grid_scat, blk, 0, stream>>>(bufU, ei_p, aggP);  // u1 -> articles
    sage_node<false, true><<<grid_node, blk, 0, stream>>>(
        aggP, cnt_p, bufA, c2p_wl, c2p_bl, c2p_wr, nullptr, w_out, b_out,
        (float*)d_out);

    (void)in_sizes; (void)n_in; (void)out_size; (void)ws_size;
}

// Round 4
// 1564.942 us; speedup vs baseline: 1.8496x; 1.1633x over previous
//
#include <hip/hip_runtime.h>

#define N_NODES 100000
#define EDGES   1600000
#define H 64
#define ROWS 32      // rows per sage_node block
#define OFFPAD 100352  // padded int array stride (mult of 1024*98 coverage)

// ---------- input projection: out = relu(x @ W^T + b); x:[N,D] f32, W:[64,D] f32 ----------
template<int D, int KT>
__global__ __launch_bounds__(256) void proj_relu(
    const float* __restrict__ x, const float* __restrict__ w,
    const float* __restrict__ b, float* __restrict__ out)
{
    __shared__ float Wt[KT * 64];
    __shared__ float Xs[16 * KT];
    const int tid  = threadIdx.x;
    const int base = blockIdx.x * 16;
    const int j  = tid & 63;
    const int r0 = (tid >> 6) * 4;
    float a0 = 0.f, a1 = 0.f, a2 = 0.f, a3 = 0.f;

    for (int k0 = 0; k0 < D; k0 += KT) {
        for (int idx = tid; idx < KT * 64; idx += 256) {
            int jj = idx / KT;
            int kk = idx - jj * KT;
            Wt[kk * 64 + jj] = w[(size_t)jj * D + k0 + kk];
        }
        for (int r = 0; r < 16; ++r) {
            const float* xr = x + (size_t)(base + r) * D + k0;
            for (int kk = tid; kk < KT; kk += 256) Xs[r * KT + kk] = xr[kk];
        }
        __syncthreads();
        for (int kk = 0; kk < KT; ++kk) {
            float wv = Wt[kk * 64 + j];
            a0 += Xs[(r0 + 0) * KT + kk] * wv;
            a1 += Xs[(r0 + 1) * KT + kk] * wv;
            a2 += Xs[(r0 + 2) * KT + kk] * wv;
            a3 += Xs[(r0 + 3) * KT + kk] * wv;
        }
        __syncthreads();
    }
    float bv = b[j];
    out[(size_t)(base + r0 + 0) * H + j] = fmaxf(a0 + bv, 0.f);
    out[(size_t)(base + r0 + 1) * H + j] = fmaxf(a1 + bv, 0.f);
    out[(size_t)(base + r0 + 2) * H + j] = fmaxf(a2 + bv, 0.f);
    out[(size_t)(base + r0 + 3) * H + j] = fmaxf(a3 + bv, 0.f);
}

// ---------- CSR build: histogram of dst ----------
__global__ __launch_bounds__(256) void hist_dst(
    const int* __restrict__ ei, int* __restrict__ hist)
{
    int e = blockIdx.x * 256 + threadIdx.x;
    if (e < EDGES) atomicAdd(&hist[ei[EDGES + e]], 1);
}

// ---------- CSR build: single-block exclusive scan over N_NODES (writes off + cursor copy) ----------
__global__ __launch_bounds__(1024) void scan_off(
    const int* __restrict__ hist, int* __restrict__ off, int* __restrict__ cur)
{
    __shared__ int sums[1024];
    const int t = threadIdx.x;
    const int CH = 98;                       // 1024*98 >= N_NODES
    const int base = t * CH;
    int s = 0;
    for (int k = 0; k < CH; ++k) {
        int i = base + k;
        if (i < N_NODES) s += hist[i];
    }
    sums[t] = s;
    __syncthreads();
    for (int d = 1; d < 1024; d <<= 1) {     // inclusive Hillis-Steele
        int v = (t >= d) ? sums[t - d] : 0;
        __syncthreads();
        if (t >= d) sums[t] += v;
        __syncthreads();
    }
    int run = sums[t] - s;                   // exclusive prefix of this chunk
    for (int k = 0; k < CH; ++k) {
        int i = base + k;
        if (i < N_NODES) {
            off[i] = run; cur[i] = run;
            run += hist[i];
        }
    }
    if (t == 0) off[N_NODES] = EDGES;
}

// ---------- CSR build: fill src lists ----------
__global__ __launch_bounds__(256) void fill_csr(
    const int* __restrict__ ei, int* __restrict__ cur, int* __restrict__ csr)
{
    int e = blockIdx.x * 256 + threadIdx.x;
    if (e < EDGES) {
        int d = ei[EDGES + e];
        int pos = atomicAdd(&cur[d], 1);
        csr[pos] = ei[e];
    }
}

// ---------- gather-reduce: wave per dst node; agg[dst] = mean of feat[src] ----------
__global__ __launch_bounds__(256) void gather_mean(
    const float* __restrict__ feat, const int* __restrict__ off,
    const int* __restrict__ csr, float* __restrict__ agg)
{
    const int node = (blockIdx.x * 256 + threadIdx.x) >> 6;   // grid sized exactly
    const int lane = threadIdx.x & 63;
    const int grp  = lane >> 4;          // 4 edges in flight
    const int fb   = (lane & 15) * 4;    // float4 feature base
    const int beg = off[node], end = off[node + 1];
    float4 acc = make_float4(0.f, 0.f, 0.f, 0.f);
    for (int e = beg + grp; e < end; e += 4) {
        int s = csr[e];
        const float4 v = *(const float4*)&feat[(size_t)s * H + fb];
        acc.x += v.x; acc.y += v.y; acc.z += v.z; acc.w += v.w;
    }
    // butterfly-reduce across the 4 groups (lane bits 4,5); feature index preserved
    #pragma unroll
    for (int m = 16; m <= 32; m <<= 1) {
        acc.x += __shfl_xor(acc.x, m, 64);
        acc.y += __shfl_xor(acc.y, m, 64);
        acc.z += __shfl_xor(acc.z, m, 64);
        acc.w += __shfl_xor(acc.w, m, 64);
    }
    const float inv = 1.0f / fmaxf((float)(end - beg), 1.0f);
    acc.x *= inv; acc.y *= inv; acc.z *= inv; acc.w *= inv;
    if (grp == 0) *(float4*)&agg[(size_t)node * H + fb] = acc;
}

// ---------- fold conv2+head: Wl'=w_out@c2p_wl, Wr'=w_out@c2p_wr, b'=w_out@c2p_bl+b_out ----------
__global__ __launch_bounds__(256) void fold_head(
    const float* __restrict__ w_out, const float* __restrict__ wl2,
    const float* __restrict__ wr2, const float* __restrict__ bl2,
    const float* __restrict__ b_out, float* __restrict__ headW)
{
    const int t = threadIdx.x;
    if (t < 128) {
        int o = t >> 6, j = t & 63;
        float s = 0.f;
        for (int h = 0; h < 64; ++h) s += w_out[o * 64 + h] * wl2[h * 64 + j];
        headW[o * 64 + j] = s;
    } else {
        int idx = t - 128, o = idx >> 6, j = idx & 63;
        float s = 0.f;
        for (int h = 0; h < 64; ++h) s += w_out[o * 64 + h] * wr2[h * 64 + j];
        headW[128 + o * 64 + j] = s;
    }
    if (t < 2) {
        float s = b_out[t];
        for (int h = 0; h < 64; ++h) s += w_out[t * 64 + h] * bl2[h];
        headW[256 + t] = s;
    }
}

// ---------- SAGE node update: v = relu( agg_mean @ Wl^T + bl + xdst @ Wr^T ) ----------
// ZHEAD=false: write v (64-dim) to out (in-place over xdst is safe: row-local).
// ZHEAD=true : write only z = v @ Wl'^T (2-dim) using headW[0..127].
template<bool ZHEAD>
__global__ __launch_bounds__(256) void sage_node(
    const float* __restrict__ agg, const float* __restrict__ xdst,
    const float* __restrict__ wl, const float* __restrict__ bl,
    const float* __restrict__ wr,
    float* __restrict__ out,
    const float* __restrict__ headW, float* __restrict__ z)
{
    __shared__ float Wlt[64 * 64], Wrt[64 * 64];   // rotate-swizzled transpose
    __shared__ float Ms[ROWS * 64], Xs[ROWS * 64];

    const int tid  = threadIdx.x;
    const int base = blockIdx.x * ROWS;

    for (int idx = tid; idx < 4096; idx += 256) {
        int jj = idx >> 6, kk = idx & 63;
        int js = (jj + kk) & 63;
        Wlt[kk * 64 + js] = wl[idx];
        Wrt[kk * 64 + js] = wr[idx];
    }
    __syncthreads();
    for (int i = tid; i < ROWS * 64; i += 256) {
        int r = i >> 6, jj = i & 63;
        Ms[i] = agg[(size_t)(base + r) * H + jj];
        Xs[i] = xdst[(size_t)(base + r) * H + jj];
    }
    __syncthreads();

    const int j  = tid & 63;
    const int r0 = (tid >> 6) * 8;
    float acc[8];
    {
        const float bv = bl[j];
        #pragma unroll
        for (int i = 0; i < 8; ++i) acc[i] = bv;
    }
    for (int k0 = 0; k0 < 64; k0 += 4) {
        float wlv[4], wrv[4];
        #pragma unroll
        for (int kk = 0; kk < 4; ++kk) {
            const int k = k0 + kk;
            const int js = (j + k) & 63;
            wlv[kk] = Wlt[k * 64 + js];
            wrv[kk] = Wrt[k * 64 + js];
        }
        #pragma unroll
        for (int i = 0; i < 8; ++i) {
            const float4 mv = *(const float4*)&Ms[(r0 + i) * 64 + k0];
            const float4 xv = *(const float4*)&Xs[(r0 + i) * 64 + k0];
            acc[i] += mv.x * wlv[0] + mv.y * wlv[1] + mv.z * wlv[2] + mv.w * wlv[3];
            acc[i] += xv.x * wrv[0] + xv.y * wrv[1] + xv.z * wrv[2] + xv.w * wrv[3];
        }
    }

    if (!ZHEAD) {
        #pragma unroll
        for (int i = 0; i < 8; ++i)
            out[(size_t)(base + r0 + i) * H + j] = fmaxf(acc[i], 0.f);
    } else {
        __syncthreads();                       // done reading Ms
        #pragma unroll
        for (int i = 0; i < 8; ++i)
            Ms[(r0 + i) * 64 + j] = fmaxf(acc[i], 0.f);   // u1 rows in LDS
        __syncthreads();
        if (tid < 2 * ROWS) {
            const int r = tid >> 1, o = tid & 1;
            float v = 0.f;
            for (int k = 0; k < 64; ++k)
                v += Ms[r * 64 + k] * headW[o * 64 + k];
            z[(size_t)(base + r) * 2 + o] = v;
        }
    }
}

// ---------- final: out[n] = mean_p(z) + a1[n] @ Wr'^T + b' ; wave per article ----------
__global__ __launch_bounds__(256) void final_head(
    const int* __restrict__ off, const int* __restrict__ csr,
    const float* __restrict__ z, const float* __restrict__ a1,
    const float* __restrict__ headW, float* __restrict__ out)
{
    const int node = (blockIdx.x * 256 + threadIdx.x) >> 6;
    const int lane = threadIdx.x & 63;
    const int beg = off[node], end = off[node + 1];
    float z0 = 0.f, z1 = 0.f;
    for (int e = beg + lane; e < end; e += 64) {
        int s = csr[e];
        const float2 zv = *(const float2*)&z[(size_t)s * 2];
        z0 += zv.x; z1 += zv.y;
    }
    const float av = a1[(size_t)node * H + lane];
    float p0 = av * headW[128 + lane];
    float p1 = av * headW[192 + lane];
    #pragma unroll
    for (int m = 1; m <= 32; m <<= 1) {
        z0 += __shfl_xor(z0, m, 64);
        z1 += __shfl_xor(z1, m, 64);
        p0 += __shfl_xor(p0, m, 64);
        p1 += __shfl_xor(p1, m, 64);
    }
    if (lane == 0) {
        const float inv = 1.0f / fmaxf((float)(end - beg), 1.0f);
        float2 o;
        o.x = z0 * inv + p0 + headW[256];
        o.y = z1 * inv + p1 + headW[257];
        *(float2*)&out[(size_t)node * 2] = o;
    }
}

extern "C" void kernel_launch(void* const* d_in, const int* in_sizes, int n_in,
                              void* d_out, int out_size, void* d_ws, size_t ws_size,
                              hipStream_t stream) {
    const float* x_a    = (const float*)d_in[0];
    const float* x_u    = (const float*)d_in[1];
    const int*   ei_p   = (const int*)d_in[2];
    const int*   ei_b   = (const int*)d_in[3];
    const float* w_in_a = (const float*)d_in[4];
    const float* b_in_a = (const float*)d_in[5];
    const float* w_in_u = (const float*)d_in[6];
    const float* b_in_u = (const float*)d_in[7];
    const float* c1p_wl = (const float*)d_in[8];
    const float* c1p_bl = (const float*)d_in[9];
    const float* c1p_wr = (const float*)d_in[10];
    const float* c1b_wl = (const float*)d_in[11];
    const float* c1b_bl = (const float*)d_in[12];
    const float* c1b_wr = (const float*)d_in[13];
    const float* c2p_wl = (const float*)d_in[14];
    const float* c2p_bl = (const float*)d_in[15];
    const float* c2p_wr = (const float*)d_in[16];
    const float* w_out  = (const float*)d_in[20];
    const float* b_out  = (const float*)d_in[21];

    const size_t NF = (size_t)N_NODES * H;
    float* bufA  = (float*)d_ws;          // a -> a1 (in-place)
    float* bufU  = bufA + NF;             // u
    float* agg   = bufU + NF;             // shared agg buffer (sequenced)
    float* z     = agg + NF;              // [N,2]
    float* headW = z + 2 * N_NODES;       // 258 floats (pad 512)
    int* off_p  = (int*)(headW + 512);
    int* off_b  = off_p + OFFPAD;
    int* cur_p  = off_b + OFFPAD;
    int* cur_b  = cur_p + OFFPAD;
    int* hist_p = cur_b + OFFPAD;
    int* hist_b = hist_p + OFFPAD;
    int* csr_p  = hist_b + OFFPAD;
    int* csr_b  = csr_p + EDGES;          // total ~93 MB

    const dim3 blk(256);
    const int grid_edge = EDGES / 256;       // 6250
    const int grid_proj = N_NODES / 16;      // 6250
    const int grid_node = N_NODES / ROWS;    // 3125
    const int grid_wave = N_NODES / 4;       // 25000 (wave per node)

    // --- CSR build for both edge types ---
    hipMemsetAsync(hist_p, 0, 2 * OFFPAD * sizeof(int), stream);
    hist_dst<<<grid_edge, blk, 0, stream>>>(ei_p, hist_p);
    hist_dst<<<grid_edge, blk, 0, stream>>>(ei_b, hist_b);
    scan_off<<<1, 1024, 0, stream>>>(hist_p, off_p, cur_p);
    scan_off<<<1, 1024, 0, stream>>>(hist_b, off_b, cur_b);
    fill_csr<<<grid_edge, blk, 0, stream>>>(ei_p, cur_p, csr_p);
    fill_csr<<<grid_edge, blk, 0, stream>>>(ei_b, cur_b, csr_b);

    // --- input projections ---
    proj_relu<300, 100><<<grid_proj, blk, 0, stream>>>(x_a, w_in_a, b_in_a, bufA);
    proj_relu<64, 64>  <<<grid_proj, blk, 0, stream>>>(x_u, w_in_u, b_in_u, bufU);

    // --- fold conv2 + output head into 2-dim maps ---
    fold_head<<<1, blk, 0, stream>>>(w_out, c2p_wl, c2p_wr, c2p_bl, b_out, headW);

    // --- user side: agg articles (ei_pb), compute z = relu(sage)@Wl'^T (u1 never stored) ---
    gather_mean<<<grid_wave, blk, 0, stream>>>(bufA, off_b, csr_b, agg);
    sage_node<true><<<grid_node, blk, 0, stream>>>(
        agg, bufU, c1b_wl, c1b_bl, c1b_wr, nullptr, headW, z);

    // --- article side: agg users (ei_posts), a1 in-place over bufA ---
    gather_mean<<<grid_wave, blk, 0, stream>>>(bufU, off_p, csr_p, agg);
    sage_node<false><<<grid_node, blk, 0, stream>>>(
        agg, bufA, c1p_wl, c1p_bl, c1p_wr, bufA, nullptr, nullptr);

    // --- final: 2-dim aggregation of z + a1 head ---
    final_head<<<grid_wave, blk, 0, stream>>>(off_p, csr_p, z, bufA, headW, (float*)d_out);

    (void)in_sizes; (void)n_in; (void)out_size; (void)ws_size;
}

// Round 5
// 1338.198 us; speedup vs baseline: 2.1630x; 1.1694x over previous
//
#include <hip/hip_runtime.h>

#define N_NODES 100000
#define EDGES   1600000
#define H 64
#define ROWS 32      // rows per sage_node block
#define OFFPAD 100352

// ---------- input projection v2: out = relu(x @ W^T + b); 32 rows/block ----------
// Weights staged as float4 with rotate swizzle at float4 granularity:
//   Wq[k4*64 + ((j+k4)&63)] = W[j][4k4..4k4+3]
// staging: consecutive lanes write consecutive b128 slots (conflict-free);
// compute: consecutive lanes read consecutive b128 slots (conflict-free);
// X reads are float4 wave-broadcasts. 9 LDS instrs per 32 FMAs.
template<int D, int KT>
__global__ __launch_bounds__(256) void proj_relu(
    const float* __restrict__ x, const float* __restrict__ w,
    const float* __restrict__ b, float* __restrict__ out)
{
    constexpr int KT4 = KT / 4;
    __shared__ float4 Wq[KT4 * 64];
    __shared__ __align__(16) float Xs[32 * KT];
    const int tid  = threadIdx.x;
    const int base = blockIdx.x * 32;
    const int j  = tid & 63;
    const int r0 = (tid >> 6) * 8;
    float acc[8];
    #pragma unroll
    for (int i = 0; i < 8; ++i) acc[i] = 0.f;

    for (int k0 = 0; k0 < D; k0 += KT) {
        for (int idx = tid; idx < KT4 * 64; idx += 256) {
            const int jj = idx & 63, k4 = idx >> 6;
            Wq[(k4 << 6) | ((jj + k4) & 63)] =
                *(const float4*)&w[(size_t)jj * D + k0 + (k4 << 2)];
        }
        for (int i = tid; i < 32 * KT; i += 256) {
            const int r = i / KT, k = i - r * KT;
            Xs[i] = x[(size_t)(base + r) * D + k0 + k];
        }
        __syncthreads();
        for (int k4 = 0; k4 < KT4; ++k4) {
            const float4 wv = Wq[(k4 << 6) | ((j + k4) & 63)];
            #pragma unroll
            for (int i = 0; i < 8; ++i) {
                const float4 xv = *(const float4*)&Xs[(r0 + i) * KT + (k4 << 2)];
                acc[i] += xv.x * wv.x + xv.y * wv.y + xv.z * wv.z + xv.w * wv.w;
            }
        }
        __syncthreads();
    }
    const float bv = b[j];
    #pragma unroll
    for (int i = 0; i < 8; ++i)
        out[(size_t)(base + r0 + i) * H + j] = fmaxf(acc[i] + bv, 0.f);
}

// ---------- CSR build: histogram of dst ----------
__global__ __launch_bounds__(256) void hist_dst(
    const int* __restrict__ ei, int* __restrict__ hist)
{
    int e = blockIdx.x * 256 + threadIdx.x;
    if (e < EDGES) atomicAdd(&hist[ei[EDGES + e]], 1);
}

// ---------- CSR build: single-block scan ----------
__global__ __launch_bounds__(1024) void scan_off(
    const int* __restrict__ hist, int* __restrict__ off, int* __restrict__ cur)
{
    __shared__ int sums[1024];
    const int t = threadIdx.x;
    const int CH = 98;
    const int base = t * CH;
    int s = 0;
    for (int k = 0; k < CH; ++k) {
        int i = base + k;
        if (i < N_NODES) s += hist[i];
    }
    sums[t] = s;
    __syncthreads();
    for (int d = 1; d < 1024; d <<= 1) {
        int v = (t >= d) ? sums[t - d] : 0;
        __syncthreads();
        if (t >= d) sums[t] += v;
        __syncthreads();
    }
    int run = sums[t] - s;
    for (int k = 0; k < CH; ++k) {
        int i = base + k;
        if (i < N_NODES) {
            off[i] = run; cur[i] = run;
            run += hist[i];
        }
    }
    if (t == 0) off[N_NODES] = EDGES;
}

// ---------- CSR build: fill src lists ----------
__global__ __launch_bounds__(256) void fill_csr(
    const int* __restrict__ ei, int* __restrict__ cur, int* __restrict__ csr)
{
    int e = blockIdx.x * 256 + threadIdx.x;
    if (e < EDGES) {
        int d = ei[EDGES + e];
        int pos = atomicAdd(&cur[d], 1);
        csr[pos] = ei[e];
    }
}

// ---------- gather-reduce: wave per dst node ----------
__global__ __launch_bounds__(256) void gather_mean(
    const float* __restrict__ feat, const int* __restrict__ off,
    const int* __restrict__ csr, float* __restrict__ agg)
{
    const int node = (blockIdx.x * 256 + threadIdx.x) >> 6;
    const int lane = threadIdx.x & 63;
    const int grp  = lane >> 4;
    const int fb   = (lane & 15) * 4;
    const int beg = off[node], end = off[node + 1];
    float4 acc = make_float4(0.f, 0.f, 0.f, 0.f);
    for (int e = beg + grp; e < end; e += 4) {
        int s = csr[e];
        const float4 v = *(const float4*)&feat[(size_t)s * H + fb];
        acc.x += v.x; acc.y += v.y; acc.z += v.z; acc.w += v.w;
    }
    #pragma unroll
    for (int m = 16; m <= 32; m <<= 1) {
        acc.x += __shfl_xor(acc.x, m, 64);
        acc.y += __shfl_xor(acc.y, m, 64);
        acc.z += __shfl_xor(acc.z, m, 64);
        acc.w += __shfl_xor(acc.w, m, 64);
    }
    const float inv = 1.0f / fmaxf((float)(end - beg), 1.0f);
    acc.x *= inv; acc.y *= inv; acc.z *= inv; acc.w *= inv;
    if (grp == 0) *(float4*)&agg[(size_t)node * H + fb] = acc;
}

// ---------- fold conv2+head ----------
__global__ __launch_bounds__(256) void fold_head(
    const float* __restrict__ w_out, const float* __restrict__ wl2,
    const float* __restrict__ wr2, const float* __restrict__ bl2,
    const float* __restrict__ b_out, float* __restrict__ headW)
{
    const int t = threadIdx.x;
    if (t < 128) {
        int o = t >> 6, j = t & 63;
        float s = 0.f;
        for (int h = 0; h < 64; ++h) s += w_out[o * 64 + h] * wl2[h * 64 + j];
        headW[o * 64 + j] = s;
    } else {
        int idx = t - 128, o = idx >> 6, j = idx & 63;
        float s = 0.f;
        for (int h = 0; h < 64; ++h) s += w_out[o * 64 + h] * wr2[h * 64 + j];
        headW[128 + o * 64 + j] = s;
    }
    if (t < 2) {
        float s = b_out[t];
        for (int h = 0; h < 64; ++h) s += w_out[t * 64 + h] * bl2[h];
        headW[256 + t] = s;
    }
}

// ---------- SAGE node update ----------
template<bool ZHEAD>
__global__ __launch_bounds__(256) void sage_node(
    const float* __restrict__ agg, const float* __restrict__ xdst,
    const float* __restrict__ wl, const float* __restrict__ bl,
    const float* __restrict__ wr,
    float* __restrict__ out,
    const float* __restrict__ headW, float* __restrict__ z)
{
    __shared__ float Wlt[64 * 64], Wrt[64 * 64];
    __shared__ __align__(16) float Ms[ROWS * 64], Xs[ROWS * 64];

    const int tid  = threadIdx.x;
    const int base = blockIdx.x * ROWS;

    for (int idx = tid; idx < 4096; idx += 256) {
        int jj = idx >> 6, kk = idx & 63;
        int js = (jj + kk) & 63;
        Wlt[kk * 64 + js] = wl[idx];
        Wrt[kk * 64 + js] = wr[idx];
    }
    __syncthreads();
    for (int i = tid; i < ROWS * 64; i += 256) {
        int r = i >> 6, jj = i & 63;
        Ms[i] = agg[(size_t)(base + r) * H + jj];
        Xs[i] = xdst[(size_t)(base + r) * H + jj];
    }
    __syncthreads();

    const int j  = tid & 63;
    const int r0 = (tid >> 6) * 8;
    float acc[8];
    {
        const float bv = bl[j];
        #pragma unroll
        for (int i = 0; i < 8; ++i) acc[i] = bv;
    }
    for (int k0 = 0; k0 < 64; k0 += 4) {
        float wlv[4], wrv[4];
        #pragma unroll
        for (int kk = 0; kk < 4; ++kk) {
            const int k = k0 + kk;
            const int js = (j + k) & 63;
            wlv[kk] = Wlt[k * 64 + js];
            wrv[kk] = Wrt[k * 64 + js];
        }
        #pragma unroll
        for (int i = 0; i < 8; ++i) {
            const float4 mv = *(const float4*)&Ms[(r0 + i) * 64 + k0];
            const float4 xv = *(const float4*)&Xs[(r0 + i) * 64 + k0];
            acc[i] += mv.x * wlv[0] + mv.y * wlv[1] + mv.z * wlv[2] + mv.w * wlv[3];
            acc[i] += xv.x * wrv[0] + xv.y * wrv[1] + xv.z * wrv[2] + xv.w * wrv[3];
        }
    }

    if (!ZHEAD) {
        #pragma unroll
        for (int i = 0; i < 8; ++i)
            out[(size_t)(base + r0 + i) * H + j] = fmaxf(acc[i], 0.f);
    } else {
        __syncthreads();
        #pragma unroll
        for (int i = 0; i < 8; ++i)
            Ms[(r0 + i) * 64 + j] = fmaxf(acc[i], 0.f);
        __syncthreads();
        if (tid < 2 * ROWS) {
            const int r = tid >> 1, o = tid & 1;
            float v = 0.f;
            for (int k = 0; k < 64; ++k)
                v += Ms[r * 64 + k] * headW[o * 64 + k];
            z[(size_t)(base + r) * 2 + o] = v;
        }
    }
}

// ---------- final: out[n] = mean_p(z) + a1[n] @ Wr'^T + b' ----------
__global__ __launch_bounds__(256) void final_head(
    const int* __restrict__ off, const int* __restrict__ csr,
    const float* __restrict__ z, const float* __restrict__ a1,
    const float* __restrict__ headW, float* __restrict__ out)
{
    const int node = (blockIdx.x * 256 + threadIdx.x) >> 6;
    const int lane = threadIdx.x & 63;
    const int beg = off[node], end = off[node + 1];
    float z0 = 0.f, z1 = 0.f;
    for (int e = beg + lane; e < end; e += 64) {
        int s = csr[e];
        const float2 zv = *(const float2*)&z[(size_t)s * 2];
        z0 += zv.x; z1 += zv.y;
    }
    const float av = a1[(size_t)node * H + lane];
    float p0 = av * headW[128 + lane];
    float p1 = av * headW[192 + lane];
    #pragma unroll
    for (int m = 1; m <= 32; m <<= 1) {
        z0 += __shfl_xor(z0, m, 64);
        z1 += __shfl_xor(z1, m, 64);
        p0 += __shfl_xor(p0, m, 64);
        p1 += __shfl_xor(p1, m, 64);
    }
    if (lane == 0) {
        const float inv = 1.0f / fmaxf((float)(end - beg), 1.0f);
        float2 o;
        o.x = z0 * inv + p0 + headW[256];
        o.y = z1 * inv + p1 + headW[257];
        *(float2*)&out[(size_t)node * 2] = o;
    }
}

extern "C" void kernel_launch(void* const* d_in, const int* in_sizes, int n_in,
                              void* d_out, int out_size, void* d_ws, size_t ws_size,
                              hipStream_t stream) {
    const float* x_a    = (const float*)d_in[0];
    const float* x_u    = (const float*)d_in[1];
    const int*   ei_p   = (const int*)d_in[2];
    const int*   ei_b   = (const int*)d_in[3];
    const float* w_in_a = (const float*)d_in[4];
    const float* b_in_a = (const float*)d_in[5];
    const float* w_in_u = (const float*)d_in[6];
    const float* b_in_u = (const float*)d_in[7];
    const float* c1p_wl = (const float*)d_in[8];
    const float* c1p_bl = (const float*)d_in[9];
    const float* c1p_wr = (const float*)d_in[10];
    const float* c1b_wl = (const float*)d_in[11];
    const float* c1b_bl = (const float*)d_in[12];
    const float* c1b_wr = (const float*)d_in[13];
    const float* c2p_wl = (const float*)d_in[14];
    const float* c2p_bl = (const float*)d_in[15];
    const float* c2p_wr = (const float*)d_in[16];
    const float* w_out  = (const float*)d_in[20];
    const float* b_out  = (const float*)d_in[21];

    const size_t NF = (size_t)N_NODES * H;
    float* bufA  = (float*)d_ws;
    float* bufU  = bufA + NF;
    float* agg   = bufU + NF;
    float* z     = agg + NF;
    float* headW = z + 2 * N_NODES;
    int* off_p  = (int*)(headW + 512);
    int* off_b  = off_p + OFFPAD;
    int* cur_p  = off_b + OFFPAD;
    int* cur_b  = cur_p + OFFPAD;
    int* hist_p = cur_b + OFFPAD;
    int* hist_b = hist_p + OFFPAD;
    int* csr_p  = hist_b + OFFPAD;
    int* csr_b  = csr_p + EDGES;

    const dim3 blk(256);
    const int grid_edge = EDGES / 256;
    const int grid_proj = N_NODES / 32;      // 3125
    const int grid_node = N_NODES / ROWS;    // 3125
    const int grid_wave = N_NODES / 4;       // 25000

    hipMemsetAsync(hist_p, 0, 2 * OFFPAD * sizeof(int), stream);
    hist_dst<<<grid_edge, blk, 0, stream>>>(ei_p, hist_p);
    hist_dst<<<grid_edge, blk, 0, stream>>>(ei_b, hist_b);
    scan_off<<<1, 1024, 0, stream>>>(hist_p, off_p, cur_p);
    scan_off<<<1, 1024, 0, stream>>>(hist_b, off_b, cur_b);
    fill_csr<<<grid_edge, blk, 0, stream>>>(ei_p, cur_p, csr_p);
    fill_csr<<<grid_edge, blk, 0, stream>>>(ei_b, cur_b, csr_b);

    proj_relu<300, 100><<<grid_proj, blk, 0, stream>>>(x_a, w_in_a, b_in_a, bufA);
    proj_relu<64, 64>  <<<grid_proj, blk, 0, stream>>>(x_u, w_in_u, b_in_u, bufU);

    fold_head<<<1, blk, 0, stream>>>(w_out, c2p_wl, c2p_wr, c2p_bl, b_out, headW);

    // user side: agg articles (ei_pb), z = relu(sage)@Wl'^T (u1 never stored)
    gather_mean<<<grid_wave, blk, 0, stream>>>(bufA, off_b, csr_b, agg);
    sage_node<true><<<grid_node, blk, 0, stream>>>(
        agg, bufU, c1b_wl, c1b_bl, c1b_wr, nullptr, headW, z);

    // article side: agg users (ei_posts), a1 in-place over bufA
    gather_mean<<<grid_wave, blk, 0, stream>>>(bufU, off_p, csr_p, agg);
    sage_node<false><<<grid_node, blk, 0, stream>>>(
        agg, bufA, c1p_wl, c1p_bl, c1p_wr, bufA, nullptr, nullptr);

    final_head<<<grid_wave, blk, 0, stream>>>(off_p, csr_p, z, bufA, headW, (float*)d_out);

    (void)in_sizes; (void)n_in; (void)out_size; (void)ws_size;
}

// Round 6
// 835.923 us; speedup vs baseline: 3.4627x; 1.6009x over previous
//
#include <hip/hip_runtime.h>

#define N_NODES 100000
#define EDGES   1600000
#define H 64
#define ROWS 32      // rows per sage_node block
#define OFFPAD 100352
#define SCAN_CH 512
#define SCAN_BLKS 196   // 196*512 = 100352 >= N_NODES

// ---------- input projection: out = relu(x @ W^T + b); 32 rows/block ----------
template<int D, int KT>
__global__ __launch_bounds__(256) void proj_relu(
    const float* __restrict__ x, const float* __restrict__ w,
    const float* __restrict__ b, float* __restrict__ out)
{
    constexpr int KT4 = KT / 4;
    __shared__ float4 Wq[KT4 * 64];
    __shared__ __align__(16) float Xs[32 * KT];
    const int tid  = threadIdx.x;
    const int base = blockIdx.x * 32;
    const int j  = tid & 63;
    const int r0 = (tid >> 6) * 8;
    float acc[8];
    #pragma unroll
    for (int i = 0; i < 8; ++i) acc[i] = 0.f;

    for (int k0 = 0; k0 < D; k0 += KT) {
        for (int idx = tid; idx < KT4 * 64; idx += 256) {
            const int jj = idx & 63, k4 = idx >> 6;
            Wq[(k4 << 6) | ((jj + k4) & 63)] =
                *(const float4*)&w[(size_t)jj * D + k0 + (k4 << 2)];
        }
        for (int i = tid; i < 32 * KT; i += 256) {
            const int r = i / KT, k = i - r * KT;
            Xs[i] = x[(size_t)(base + r) * D + k0 + k];
        }
        __syncthreads();
        for (int k4 = 0; k4 < KT4; ++k4) {
            const float4 wv = Wq[(k4 << 6) | ((j + k4) & 63)];
            #pragma unroll
            for (int i = 0; i < 8; ++i) {
                const float4 xv = *(const float4*)&Xs[(r0 + i) * KT + (k4 << 2)];
                acc[i] += xv.x * wv.x + xv.y * wv.y + xv.z * wv.z + xv.w * wv.w;
            }
        }
        __syncthreads();
    }
    const float bv = b[j];
    #pragma unroll
    for (int i = 0; i < 8; ++i)
        out[(size_t)(base + r0 + i) * H + j] = fmaxf(acc[i] + bv, 0.f);
}

// ---------- CSR build: histogram of dst ----------
__global__ __launch_bounds__(256) void hist_dst(
    const int* __restrict__ ei, int* __restrict__ hist)
{
    int e = blockIdx.x * 256 + threadIdx.x;
    if (e < EDGES) atomicAdd(&hist[ei[EDGES + e]], 1);
}

// ---------- device-wide scan, 3 kernels ----------
__global__ __launch_bounds__(256) void scan_partial(
    const int* __restrict__ hist, int* __restrict__ bsum)
{
    __shared__ int red[256];
    const int b = blockIdx.x, t = threadIdx.x;
    const int i0 = b * SCAN_CH + t;
    int s = 0;
    if (i0 < N_NODES) s += hist[i0];
    if (i0 + 256 < N_NODES) s += hist[i0 + 256];
    red[t] = s;
    __syncthreads();
    for (int d = 128; d > 0; d >>= 1) {
        if (t < d) red[t] += red[t + d];
        __syncthreads();
    }
    if (t == 0) bsum[b] = red[0];
}

__global__ __launch_bounds__(256) void scan_tops(
    const int* __restrict__ bsum, int* __restrict__ bpre)
{
    __shared__ int s[256];
    const int t = threadIdx.x;
    const int v = (t < SCAN_BLKS) ? bsum[t] : 0;
    s[t] = v;
    __syncthreads();
    for (int d = 1; d < 256; d <<= 1) {
        int x = (t >= d) ? s[t - d] : 0;
        __syncthreads();
        s[t] += x;
        __syncthreads();
    }
    if (t < SCAN_BLKS) bpre[t] = s[t] - v;   // exclusive
}

__global__ __launch_bounds__(512) void scan_apply(
    const int* __restrict__ hist, const int* __restrict__ bpre,
    int* __restrict__ off, int* __restrict__ cur)
{
    __shared__ int s[512];
    const int b = blockIdx.x, t = threadIdx.x;
    const int i = b * SCAN_CH + t;
    const int h = (i < N_NODES) ? hist[i] : 0;
    s[t] = h;
    __syncthreads();
    for (int d = 1; d < 512; d <<= 1) {
        int x = (t >= d) ? s[t - d] : 0;
        __syncthreads();
        s[t] += x;
        __syncthreads();
    }
    if (i < N_NODES) {
        const int excl = s[t] - h + bpre[b];
        off[i] = excl; cur[i] = excl;
    }
    if (b == 0 && t == 0) off[N_NODES] = EDGES;
}

// ---------- CSR build: fill src lists ----------
__global__ __launch_bounds__(256) void fill_csr(
    const int* __restrict__ ei, int* __restrict__ cur, int* __restrict__ csr)
{
    int e = blockIdx.x * 256 + threadIdx.x;
    if (e < EDGES) {
        int d = ei[EDGES + e];
        int pos = atomicAdd(&cur[d], 1);
        csr[pos] = ei[e];
    }
}

// ---------- gather-reduce: wave per dst node ----------
__global__ __launch_bounds__(256) void gather_mean(
    const float* __restrict__ feat, const int* __restrict__ off,
    const int* __restrict__ csr, float* __restrict__ agg)
{
    const int node = (blockIdx.x * 256 + threadIdx.x) >> 6;
    const int lane = threadIdx.x & 63;
    const int grp  = lane >> 4;
    const int fb   = (lane & 15) * 4;
    const int beg = off[node], end = off[node + 1];
    float4 acc = make_float4(0.f, 0.f, 0.f, 0.f);
    for (int e = beg + grp; e < end; e += 4) {
        int s = csr[e];
        const float4 v = *(const float4*)&feat[(size_t)s * H + fb];
        acc.x += v.x; acc.y += v.y; acc.z += v.z; acc.w += v.w;
    }
    #pragma unroll
    for (int m = 16; m <= 32; m <<= 1) {
        acc.x += __shfl_xor(acc.x, m, 64);
        acc.y += __shfl_xor(acc.y, m, 64);
        acc.z += __shfl_xor(acc.z, m, 64);
        acc.w += __shfl_xor(acc.w, m, 64);
    }
    const float inv = 1.0f / fmaxf((float)(end - beg), 1.0f);
    acc.x *= inv; acc.y *= inv; acc.z *= inv; acc.w *= inv;
    if (grp == 0) *(float4*)&agg[(size_t)node * H + fb] = acc;
}

// ---------- fold conv2+head ----------
__global__ __launch_bounds__(256) void fold_head(
    const float* __restrict__ w_out, const float* __restrict__ wl2,
    const float* __restrict__ wr2, const float* __restrict__ bl2,
    const float* __restrict__ b_out, float* __restrict__ headW)
{
    const int t = threadIdx.x;
    if (t < 128) {
        int o = t >> 6, j = t & 63;
        float s = 0.f;
        for (int h = 0; h < 64; ++h) s += w_out[o * 64 + h] * wl2[h * 64 + j];
        headW[o * 64 + j] = s;
    } else {
        int idx = t - 128, o = idx >> 6, j = idx & 63;
        float s = 0.f;
        for (int h = 0; h < 64; ++h) s += w_out[o * 64 + h] * wr2[h * 64 + j];
        headW[128 + o * 64 + j] = s;
    }
    if (t < 2) {
        float s = b_out[t];
        for (int h = 0; h < 64; ++h) s += w_out[t * 64 + h] * bl2[h];
        headW[256 + t] = s;
    }
}

// ---------- SAGE node update ----------
template<bool ZHEAD>
__global__ __launch_bounds__(256) void sage_node(
    const float* __restrict__ agg, const float* __restrict__ xdst,
    const float* __restrict__ wl, const float* __restrict__ bl,
    const float* __restrict__ wr,
    float* __restrict__ out,
    const float* __restrict__ headW, float* __restrict__ z)
{
    __shared__ float Wlt[64 * 64], Wrt[64 * 64];
    __shared__ __align__(16) float Ms[ROWS * 64], Xs[ROWS * 64];

    const int tid  = threadIdx.x;
    const int base = blockIdx.x * ROWS;

    for (int idx = tid; idx < 4096; idx += 256) {
        int jj = idx >> 6, kk = idx & 63;
        int js = (jj + kk) & 63;
        Wlt[kk * 64 + js] = wl[idx];
        Wrt[kk * 64 + js] = wr[idx];
    }
    __syncthreads();
    for (int i = tid; i < ROWS * 64; i += 256) {
        int r = i >> 6, jj = i & 63;
        Ms[i] = agg[(size_t)(base + r) * H + jj];
        Xs[i] = xdst[(size_t)(base + r) * H + jj];
    }
    __syncthreads();

    const int j  = tid & 63;
    const int r0 = (tid >> 6) * 8;
    float acc[8];
    {
        const float bv = bl[j];
        #pragma unroll
        for (int i = 0; i < 8; ++i) acc[i] = bv;
    }
    for (int k0 = 0; k0 < 64; k0 += 4) {
        float wlv[4], wrv[4];
        #pragma unroll
        for (int kk = 0; kk < 4; ++kk) {
            const int k = k0 + kk;
            const int js = (j + k) & 63;
            wlv[kk] = Wlt[k * 64 + js];
            wrv[kk] = Wrt[k * 64 + js];
        }
        #pragma unroll
        for (int i = 0; i < 8; ++i) {
            const float4 mv = *(const float4*)&Ms[(r0 + i) * 64 + k0];
            const float4 xv = *(const float4*)&Xs[(r0 + i) * 64 + k0];
            acc[i] += mv.x * wlv[0] + mv.y * wlv[1] + mv.z * wlv[2] + mv.w * wlv[3];
            acc[i] += xv.x * wrv[0] + xv.y * wrv[1] + xv.z * wrv[2] + xv.w * wrv[3];
        }
    }

    if (!ZHEAD) {
        #pragma unroll
        for (int i = 0; i < 8; ++i)
            out[(size_t)(base + r0 + i) * H + j] = fmaxf(acc[i], 0.f);
    } else {
        __syncthreads();
        #pragma unroll
        for (int i = 0; i < 8; ++i)
            Ms[(r0 + i) * 64 + j] = fmaxf(acc[i], 0.f);
        __syncthreads();
        if (tid < 2 * ROWS) {
            const int r = tid >> 1, o = tid & 1;
            float v = 0.f;
            for (int k = 0; k < 64; ++k)
                v += Ms[r * 64 + k] * headW[o * 64 + k];
            z[(size_t)(base + r) * 2 + o] = v;
        }
    }
}

// ---------- final: out[n] = mean_p(z) + a1[n] @ Wr'^T + b' ----------
__global__ __launch_bounds__(256) void final_head(
    const int* __restrict__ off, const int* __restrict__ csr,
    const float* __restrict__ z, const float* __restrict__ a1,
    const float* __restrict__ headW, float* __restrict__ out)
{
    const int node = (blockIdx.x * 256 + threadIdx.x) >> 6;
    const int lane = threadIdx.x & 63;
    const int beg = off[node], end = off[node + 1];
    float z0 = 0.f, z1 = 0.f;
    for (int e = beg + lane; e < end; e += 64) {
        int s = csr[e];
        const float2 zv = *(const float2*)&z[(size_t)s * 2];
        z0 += zv.x; z1 += zv.y;
    }
    const float av = a1[(size_t)node * H + lane];
    float p0 = av * headW[128 + lane];
    float p1 = av * headW[192 + lane];
    #pragma unroll
    for (int m = 1; m <= 32; m <<= 1) {
        z0 += __shfl_xor(z0, m, 64);
        z1 += __shfl_xor(z1, m, 64);
        p0 += __shfl_xor(p0, m, 64);
        p1 += __shfl_xor(p1, m, 64);
    }
    if (lane == 0) {
        const float inv = 1.0f / fmaxf((float)(end - beg), 1.0f);
        float2 o;
        o.x = z0 * inv + p0 + headW[256];
        o.y = z1 * inv + p1 + headW[257];
        *(float2*)&out[(size_t)node * 2] = o;
    }
}

extern "C" void kernel_launch(void* const* d_in, const int* in_sizes, int n_in,
                              void* d_out, int out_size, void* d_ws, size_t ws_size,
                              hipStream_t stream) {
    const float* x_a    = (const float*)d_in[0];
    const float* x_u    = (const float*)d_in[1];
    const int*   ei_p   = (const int*)d_in[2];
    const int*   ei_b   = (const int*)d_in[3];
    const float* w_in_a = (const float*)d_in[4];
    const float* b_in_a = (const float*)d_in[5];
    const float* w_in_u = (const float*)d_in[6];
    const float* b_in_u = (const float*)d_in[7];
    const float* c1p_wl = (const float*)d_in[8];
    const float* c1p_bl = (const float*)d_in[9];
    const float* c1p_wr = (const float*)d_in[10];
    const float* c1b_wl = (const float*)d_in[11];
    const float* c1b_bl = (const float*)d_in[12];
    const float* c1b_wr = (const float*)d_in[13];
    const float* c2p_wl = (const float*)d_in[14];
    const float* c2p_bl = (const float*)d_in[15];
    const float* c2p_wr = (const float*)d_in[16];
    const float* w_out  = (const float*)d_in[20];
    const float* b_out  = (const float*)d_in[21];

    const size_t NF = (size_t)N_NODES * H;
    float* bufA  = (float*)d_ws;
    float* bufU  = bufA + NF;
    float* agg   = bufU + NF;
    float* z     = agg + NF;
    float* headW = z + 2 * N_NODES;
    int* off_p  = (int*)(headW + 512);
    int* off_b  = off_p + OFFPAD;
    int* cur_p  = off_b + OFFPAD;
    int* cur_b  = cur_p + OFFPAD;
    int* hist_p = cur_b + OFFPAD;
    int* hist_b = hist_p + OFFPAD;
    int* bsum_p = hist_b + OFFPAD;      // 256 ints each
    int* bsum_b = bsum_p + 256;
    int* bpre_p = bsum_b + 256;
    int* bpre_b = bpre_p + 256;
    int* csr_p  = bpre_b + 256;
    int* csr_b  = csr_p + EDGES;

    const dim3 blk(256);
    const int grid_edge = EDGES / 256;
    const int grid_proj = N_NODES / 32;      // 3125
    const int grid_node = N_NODES / ROWS;    // 3125
    const int grid_wave = N_NODES / 4;       // 25000

    // --- CSR build (device-wide 3-kernel scan) ---
    hipMemsetAsync(hist_p, 0, 2 * OFFPAD * sizeof(int), stream);
    hist_dst<<<grid_edge, blk, 0, stream>>>(ei_p, hist_p);
    hist_dst<<<grid_edge, blk, 0, stream>>>(ei_b, hist_b);
    scan_partial<<<SCAN_BLKS, blk, 0, stream>>>(hist_p, bsum_p);
    scan_partial<<<SCAN_BLKS, blk, 0, stream>>>(hist_b, bsum_b);
    scan_tops<<<1, blk, 0, stream>>>(bsum_p, bpre_p);
    scan_tops<<<1, blk, 0, stream>>>(bsum_b, bpre_b);
    scan_apply<<<SCAN_BLKS, 512, 0, stream>>>(hist_p, bpre_p, off_p, cur_p);
    scan_apply<<<SCAN_BLKS, 512, 0, stream>>>(hist_b, bpre_b, off_b, cur_b);
    fill_csr<<<grid_edge, blk, 0, stream>>>(ei_p, cur_p, csr_p);
    fill_csr<<<grid_edge, blk, 0, stream>>>(ei_b, cur_b, csr_b);

    proj_relu<300, 100><<<grid_proj, blk, 0, stream>>>(x_a, w_in_a, b_in_a, bufA);
    proj_relu<64, 64>  <<<grid_proj, blk, 0, stream>>>(x_u, w_in_u, b_in_u, bufU);

    fold_head<<<1, blk, 0, stream>>>(w_out, c2p_wl, c2p_wr, c2p_bl, b_out, headW);

    // user side: agg articles (ei_pb), z = relu(sage)@Wl'^T (u1 never stored)
    gather_mean<<<grid_wave, blk, 0, stream>>>(bufA, off_b, csr_b, agg);
    sage_node<true><<<grid_node, blk, 0, stream>>>(
        agg, bufU, c1b_wl, c1b_bl, c1b_wr, nullptr, headW, z);

    // article side: agg users (ei_posts), a1 in-place over bufA
    gather_mean<<<grid_wave, blk, 0, stream>>>(bufU, off_p, csr_p, agg);
    sage_node<false><<<grid_node, blk, 0, stream>>>(
        agg, bufA, c1p_wl, c1p_bl, c1p_wr, bufA, nullptr, nullptr);

    final_head<<<grid_wave, blk, 0, stream>>>(off_p, csr_p, z, bufA, headW, (float*)d_out);

    (void)in_sizes; (void)n_in; (void)out_size; (void)ws_size;
}

// Round 7
// 760.500 us; speedup vs baseline: 3.8062x; 1.0992x over previous
//
#include <hip/hip_runtime.h>

#define N_NODES 100000
#define EDGES   1600000
#define H 64
#define OFFPAD 100352
#define SCAN_CH 512
#define SCAN_BLKS 196   // 196*512 = 100352 >= N_NODES
#define ST 68           // LDS row stride in floats: float4-aligned, conflict-light

// ---------- input projection: out = relu(x @ W^T + b); 64 rows/block, 4x4 reg tiles ----------
// Xt[k][row], Wt[k][col], both stride ST. Per k: 2 ds_read_b128 -> 16 FMA.
template<int D, int KT>
__global__ __launch_bounds__(256) void proj_relu(
    const float* __restrict__ x, const float* __restrict__ w,
    const float* __restrict__ b, float* __restrict__ out)
{
    __shared__ __align__(16) float Xt[KT * ST];
    __shared__ __align__(16) float Wt[KT * ST];
    const int tid  = threadIdx.x;
    const int base = blockIdx.x * 64;
    const int col4 = (tid & 15) * 4;
    const int row4 = (tid >> 4) * 4;
    float c[4][4] = {};

    for (int k0 = 0; k0 < D; k0 += KT) {
        for (int idx = tid; idx < 64 * KT; idx += 256) {
            const int row = idx / KT, k = idx - row * KT;
            const int rr = min(base + row, N_NODES - 1);
            Xt[k * ST + row] = x[(size_t)rr * D + k0 + k];
        }
        for (int idx = tid; idx < 64 * KT; idx += 256) {
            const int col = idx / KT, k = idx - col * KT;
            Wt[k * ST + col] = w[(size_t)col * D + k0 + k];
        }
        __syncthreads();
        #pragma unroll 4
        for (int k = 0; k < KT; ++k) {
            const float4 av = *(const float4*)&Xt[k * ST + row4];
            const float4 bv = *(const float4*)&Wt[k * ST + col4];
            c[0][0] += av.x * bv.x; c[0][1] += av.x * bv.y; c[0][2] += av.x * bv.z; c[0][3] += av.x * bv.w;
            c[1][0] += av.y * bv.x; c[1][1] += av.y * bv.y; c[1][2] += av.y * bv.z; c[1][3] += av.y * bv.w;
            c[2][0] += av.z * bv.x; c[2][1] += av.z * bv.y; c[2][2] += av.z * bv.z; c[2][3] += av.z * bv.w;
            c[3][0] += av.w * bv.x; c[3][1] += av.w * bv.y; c[3][2] += av.w * bv.z; c[3][3] += av.w * bv.w;
        }
        __syncthreads();
    }
    const float4 bv = *(const float4*)&b[col4];
    #pragma unroll
    for (int i = 0; i < 4; ++i) {
        const int row = base + row4 + i;
        if (row < N_NODES) {
            float4 o;
            o.x = fmaxf(c[i][0] + bv.x, 0.f);
            o.y = fmaxf(c[i][1] + bv.y, 0.f);
            o.z = fmaxf(c[i][2] + bv.z, 0.f);
            o.w = fmaxf(c[i][3] + bv.w, 0.f);
            *(float4*)&out[(size_t)row * H + col4] = o;
        }
    }
}

// ---------- CSR build: histogram of dst ----------
__global__ __launch_bounds__(256) void hist_dst(
    const int* __restrict__ ei, int* __restrict__ hist)
{
    int e = blockIdx.x * 256 + threadIdx.x;
    if (e < EDGES) atomicAdd(&hist[ei[EDGES + e]], 1);
}

// ---------- device-wide scan, 3 kernels ----------
__global__ __launch_bounds__(256) void scan_partial(
    const int* __restrict__ hist, int* __restrict__ bsum)
{
    __shared__ int red[256];
    const int b = blockIdx.x, t = threadIdx.x;
    const int i0 = b * SCAN_CH + t;
    int s = 0;
    if (i0 < N_NODES) s += hist[i0];
    if (i0 + 256 < N_NODES) s += hist[i0 + 256];
    red[t] = s;
    __syncthreads();
    for (int d = 128; d > 0; d >>= 1) {
        if (t < d) red[t] += red[t + d];
        __syncthreads();
    }
    if (t == 0) bsum[b] = red[0];
}

__global__ __launch_bounds__(256) void scan_tops(
    const int* __restrict__ bsum, int* __restrict__ bpre)
{
    __shared__ int s[256];
    const int t = threadIdx.x;
    const int v = (t < SCAN_BLKS) ? bsum[t] : 0;
    s[t] = v;
    __syncthreads();
    for (int d = 1; d < 256; d <<= 1) {
        int x = (t >= d) ? s[t - d] : 0;
        __syncthreads();
        s[t] += x;
        __syncthreads();
    }
    if (t < SCAN_BLKS) bpre[t] = s[t] - v;
}

__global__ __launch_bounds__(512) void scan_apply(
    const int* __restrict__ hist, const int* __restrict__ bpre,
    int* __restrict__ off, int* __restrict__ cur)
{
    __shared__ int s[512];
    const int b = blockIdx.x, t = threadIdx.x;
    const int i = b * SCAN_CH + t;
    const int h = (i < N_NODES) ? hist[i] : 0;
    s[t] = h;
    __syncthreads();
    for (int d = 1; d < 512; d <<= 1) {
        int x = (t >= d) ? s[t - d] : 0;
        __syncthreads();
        s[t] += x;
        __syncthreads();
    }
    if (i < N_NODES) {
        const int excl = s[t] - h + bpre[b];
        off[i] = excl; cur[i] = excl;
    }
    if (b == 0 && t == 0) off[N_NODES] = EDGES;
}

// ---------- CSR build: fill src lists ----------
__global__ __launch_bounds__(256) void fill_csr(
    const int* __restrict__ ei, int* __restrict__ cur, int* __restrict__ csr)
{
    int e = blockIdx.x * 256 + threadIdx.x;
    if (e < EDGES) {
        int d = ei[EDGES + e];
        int pos = atomicAdd(&cur[d], 1);
        csr[pos] = ei[e];
    }
}

// ---------- gather-reduce: wave per dst node ----------
__global__ __launch_bounds__(256) void gather_mean(
    const float* __restrict__ feat, const int* __restrict__ off,
    const int* __restrict__ csr, float* __restrict__ agg)
{
    const int node = (blockIdx.x * 256 + threadIdx.x) >> 6;
    const int lane = threadIdx.x & 63;
    const int grp  = lane >> 4;
    const int fb   = (lane & 15) * 4;
    const int beg = off[node], end = off[node + 1];
    float4 acc = make_float4(0.f, 0.f, 0.f, 0.f);
    for (int e = beg + grp; e < end; e += 4) {
        int s = csr[e];
        const float4 v = *(const float4*)&feat[(size_t)s * H + fb];
        acc.x += v.x; acc.y += v.y; acc.z += v.z; acc.w += v.w;
    }
    #pragma unroll
    for (int m = 16; m <= 32; m <<= 1) {
        acc.x += __shfl_xor(acc.x, m, 64);
        acc.y += __shfl_xor(acc.y, m, 64);
        acc.z += __shfl_xor(acc.z, m, 64);
        acc.w += __shfl_xor(acc.w, m, 64);
    }
    const float inv = 1.0f / fmaxf((float)(end - beg), 1.0f);
    acc.x *= inv; acc.y *= inv; acc.z *= inv; acc.w *= inv;
    if (grp == 0) *(float4*)&agg[(size_t)node * H + fb] = acc;
}

// ---------- fold conv2+head ----------
__global__ __launch_bounds__(256) void fold_head(
    const float* __restrict__ w_out, const float* __restrict__ wl2,
    const float* __restrict__ wr2, const float* __restrict__ bl2,
    const float* __restrict__ b_out, float* __restrict__ headW)
{
    const int t = threadIdx.x;
    if (t < 128) {
        int o = t >> 6, j = t & 63;
        float s = 0.f;
        for (int h = 0; h < 64; ++h) s += w_out[o * 64 + h] * wl2[h * 64 + j];
        headW[o * 64 + j] = s;
    } else {
        int idx = t - 128, o = idx >> 6, j = idx & 63;
        float s = 0.f;
        for (int h = 0; h < 64; ++h) s += w_out[o * 64 + h] * wr2[h * 64 + j];
        headW[128 + o * 64 + j] = s;
    }
    if (t < 2) {
        float s = b_out[t];
        for (int h = 0; h < 64; ++h) s += w_out[t * 64 + h] * bl2[h];
        headW[256 + t] = s;
    }
}

// ---------- SAGE node update: 64 rows/block, 4x4 reg tiles, 2 K-passes ----------
// v = relu( agg @ Wl^T + bl + xdst @ Wr^T )  (agg is already the mean)
// pass 0: A=agg, B=wl; pass 1: A=xdst, B=wr. Same transposed-LDS scheme as proj.
// ZHEAD: z = v @ headW[0..127]^T (2-dim) instead of storing v.
template<bool ZHEAD>
__global__ __launch_bounds__(256) void sage_node(
    const float* __restrict__ agg, const float* __restrict__ xdst,
    const float* __restrict__ wl, const float* __restrict__ bl,
    const float* __restrict__ wr,
    float* __restrict__ out,
    const float* __restrict__ headW, float* __restrict__ z)
{
    __shared__ __align__(16) float At[64 * ST];
    __shared__ __align__(16) float Bt[64 * ST];
    const int tid  = threadIdx.x;
    const int base = blockIdx.x * 64;
    const int col4 = (tid & 15) * 4;
    const int row4 = (tid >> 4) * 4;
    float c[4][4];
    {
        const float4 bv = *(const float4*)&bl[col4];
        #pragma unroll
        for (int i = 0; i < 4; ++i) { c[i][0] = bv.x; c[i][1] = bv.y; c[i][2] = bv.z; c[i][3] = bv.w; }
    }

    #pragma unroll
    for (int pass = 0; pass < 2; ++pass) {
        const float* __restrict__ A = pass ? xdst : agg;
        const float* __restrict__ B = pass ? wr : wl;
        for (int idx = tid; idx < 64 * 64; idx += 256) {
            const int row = idx >> 6, k = idx & 63;
            const int rr = min(base + row, N_NODES - 1);
            At[k * ST + row] = A[(size_t)rr * H + k];
        }
        for (int idx = tid; idx < 64 * 64; idx += 256) {
            const int col = idx >> 6, k = idx & 63;
            Bt[k * ST + col] = B[col * 64 + k];
        }
        __syncthreads();
        #pragma unroll 4
        for (int k = 0; k < 64; ++k) {
            const float4 av = *(const float4*)&At[k * ST + row4];
            const float4 bv = *(const float4*)&Bt[k * ST + col4];
            c[0][0] += av.x * bv.x; c[0][1] += av.x * bv.y; c[0][2] += av.x * bv.z; c[0][3] += av.x * bv.w;
            c[1][0] += av.y * bv.x; c[1][1] += av.y * bv.y; c[1][2] += av.y * bv.z; c[1][3] += av.y * bv.w;
            c[2][0] += av.z * bv.x; c[2][1] += av.z * bv.y; c[2][2] += av.z * bv.z; c[2][3] += av.z * bv.w;
            c[3][0] += av.w * bv.x; c[3][1] += av.w * bv.y; c[3][2] += av.w * bv.z; c[3][3] += av.w * bv.w;
        }
        __syncthreads();
    }

    if (!ZHEAD) {
        #pragma unroll
        for (int i = 0; i < 4; ++i) {
            const int row = base + row4 + i;
            if (row < N_NODES) {
                float4 o;
                o.x = fmaxf(c[i][0], 0.f); o.y = fmaxf(c[i][1], 0.f);
                o.z = fmaxf(c[i][2], 0.f); o.w = fmaxf(c[i][3], 0.f);
                *(float4*)&out[(size_t)row * H + col4] = o;
            }
        }
    } else {
        // stash relu(v) row-major (stride 65) in At, then 2-dim head
        float* Us = At;   // 64*65 <= 64*ST
        #pragma unroll
        for (int i = 0; i < 4; ++i)
            #pragma unroll
            for (int jj = 0; jj < 4; ++jj)
                Us[(row4 + i) * 65 + col4 + jj] = fmaxf(c[i][jj], 0.f);
        __syncthreads();
        if (tid < 128) {
            const int r = tid & 63, o = tid >> 6;
            const int row = base + r;
            if (row < N_NODES) {
                float v = 0.f;
                for (int k = 0; k < 64; ++k)
                    v += Us[r * 65 + k] * headW[o * 64 + k];
                z[(size_t)row * 2 + o] = v;
            }
        }
    }
}

// ---------- final: out[n] = mean_p(z) + a1[n] @ Wr'^T + b' ----------
__global__ __launch_bounds__(256) void final_head(
    const int* __restrict__ off, const int* __restrict__ csr,
    const float* __restrict__ z, const float* __restrict__ a1,
    const float* __restrict__ headW, float* __restrict__ out)
{
    const int node = (blockIdx.x * 256 + threadIdx.x) >> 6;
    const int lane = threadIdx.x & 63;
    const int beg = off[node], end = off[node + 1];
    float z0 = 0.f, z1 = 0.f;
    for (int e = beg + lane; e < end; e += 64) {
        int s = csr[e];
        const float2 zv = *(const float2*)&z[(size_t)s * 2];
        z0 += zv.x; z1 += zv.y;
    }
    const float av = a1[(size_t)node * H + lane];
    float p0 = av * headW[128 + lane];
    float p1 = av * headW[192 + lane];
    #pragma unroll
    for (int m = 1; m <= 32; m <<= 1) {
        z0 += __shfl_xor(z0, m, 64);
        z1 += __shfl_xor(z1, m, 64);
        p0 += __shfl_xor(p0, m, 64);
        p1 += __shfl_xor(p1, m, 64);
    }
    if (lane == 0) {
        const float inv = 1.0f / fmaxf((float)(end - beg), 1.0f);
        float2 o;
        o.x = z0 * inv + p0 + headW[256];
        o.y = z1 * inv + p1 + headW[257];
        *(float2*)&out[(size_t)node * 2] = o;
    }
}

extern "C" void kernel_launch(void* const* d_in, const int* in_sizes, int n_in,
                              void* d_out, int out_size, void* d_ws, size_t ws_size,
                              hipStream_t stream) {
    const float* x_a    = (const float*)d_in[0];
    const float* x_u    = (const float*)d_in[1];
    const int*   ei_p   = (const int*)d_in[2];
    const int*   ei_b   = (const int*)d_in[3];
    const float* w_in_a = (const float*)d_in[4];
    const float* b_in_a = (const float*)d_in[5];
    const float* w_in_u = (const float*)d_in[6];
    const float* b_in_u = (const float*)d_in[7];
    const float* c1p_wl = (const float*)d_in[8];
    const float* c1p_bl = (const float*)d_in[9];
    const float* c1p_wr = (const float*)d_in[10];
    const float* c1b_wl = (const float*)d_in[11];
    const float* c1b_bl = (const float*)d_in[12];
    const float* c1b_wr = (const float*)d_in[13];
    const float* c2p_wl = (const float*)d_in[14];
    const float* c2p_bl = (const float*)d_in[15];
    const float* c2p_wr = (const float*)d_in[16];
    const float* w_out  = (const float*)d_in[20];
    const float* b_out  = (const float*)d_in[21];

    const size_t NF = (size_t)N_NODES * H;
    float* bufA  = (float*)d_ws;
    float* bufU  = bufA + NF;
    float* agg   = bufU + NF;
    float* z     = agg + NF;
    float* headW = z + 2 * N_NODES;
    int* off_p  = (int*)(headW + 512);
    int* off_b  = off_p + OFFPAD;
    int* cur_p  = off_b + OFFPAD;
    int* cur_b  = cur_p + OFFPAD;
    int* hist_p = cur_b + OFFPAD;
    int* hist_b = hist_p + OFFPAD;
    int* bsum_p = hist_b + OFFPAD;
    int* bsum_b = bsum_p + 256;
    int* bpre_p = bsum_b + 256;
    int* bpre_b = bpre_p + 256;
    int* csr_p  = bpre_b + 256;
    int* csr_b  = csr_p + EDGES;

    const dim3 blk(256);
    const int grid_edge = EDGES / 256;
    const int grid_gemm = (N_NODES + 63) / 64;   // 1563
    const int grid_wave = N_NODES / 4;           // 25000

    // --- CSR build ---
    hipMemsetAsync(hist_p, 0, 2 * OFFPAD * sizeof(int), stream);
    hist_dst<<<grid_edge, blk, 0, stream>>>(ei_p, hist_p);
    hist_dst<<<grid_edge, blk, 0, stream>>>(ei_b, hist_b);
    scan_partial<<<SCAN_BLKS, blk, 0, stream>>>(hist_p, bsum_p);
    scan_partial<<<SCAN_BLKS, blk, 0, stream>>>(hist_b, bsum_b);
    scan_tops<<<1, blk, 0, stream>>>(bsum_p, bpre_p);
    scan_tops<<<1, blk, 0, stream>>>(bsum_b, bpre_b);
    scan_apply<<<SCAN_BLKS, 512, 0, stream>>>(hist_p, bpre_p, off_p, cur_p);
    scan_apply<<<SCAN_BLKS, 512, 0, stream>>>(hist_b, bpre_b, off_b, cur_b);
    fill_csr<<<grid_edge, blk, 0, stream>>>(ei_p, cur_p, csr_p);
    fill_csr<<<grid_edge, blk, 0, stream>>>(ei_b, cur_b, csr_b);

    proj_relu<300, 60><<<grid_gemm, blk, 0, stream>>>(x_a, w_in_a, b_in_a, bufA);
    proj_relu<64, 64> <<<grid_gemm, blk, 0, stream>>>(x_u, w_in_u, b_in_u, bufU);

    fold_head<<<1, blk, 0, stream>>>(w_out, c2p_wl, c2p_wr, c2p_bl, b_out, headW);

    // user side: agg articles (ei_pb), z = relu(sage)@Wl'^T (u1 never stored)
    gather_mean<<<grid_wave, blk, 0, stream>>>(bufA, off_b, csr_b, agg);
    sage_node<true><<<grid_gemm, blk, 0, stream>>>(
        agg, bufU, c1b_wl, c1b_bl, c1b_wr, nullptr, headW, z);

    // article side: agg users (ei_posts), a1 in-place over bufA
    gather_mean<<<grid_wave, blk, 0, stream>>>(bufU, off_p, csr_p, agg);
    sage_node<false><<<grid_gemm, blk, 0, stream>>>(
        agg, bufA, c1p_wl, c1p_bl, c1p_wr, bufA, nullptr, nullptr);

    final_head<<<grid_wave, blk, 0, stream>>>(off_p, csr_p, z, bufA, headW, (float*)d_out);

    (void)in_sizes; (void)n_in; (void)out_size; (void)ws_size;
}

// Round 8
// 696.998 us; speedup vs baseline: 4.1529x; 1.0911x over previous
//
#include <hip/hip_runtime.h>

#define N_NODES 100000
#define EDGES   1600000
#define H 64
#define OFFPAD 100352
#define SCAN_CH 512
#define SCAN_BLKS 196   // 196*512 = 100352 >= N_NODES
#define ST 68           // fp32 LDS row stride (sage)

typedef unsigned int u32;
typedef short bf16x8 __attribute__((ext_vector_type(8)));
typedef float f32x4  __attribute__((ext_vector_type(4)));

// RNE fp32 -> bf16 split: x ~= hi + lo (both bf16), |err| ~ 2^-17 |x|
__device__ __forceinline__ void bfsplit(float x, u32& h, u32& lo) {
    union { float f; u32 u; } c; c.f = x;
    u32 hu = (c.u + 0x7fffu + ((c.u >> 16) & 1u)) & 0xffff0000u;
    h = hu >> 16;
    union { u32 u; float f; } hb; hb.u = hu;
    union { float f; u32 u; } r; r.f = x - hb.f;
    lo = (r.u + 0x7fffu + ((r.u >> 16) & 1u)) >> 16;
}

// ---------- input projection via MFMA: out = relu(x @ W^T + b) ----------
// 64 rows/block, 256 thr = 4 waves; wave w owns rows [16w,16w+16) x all 64 cols.
// LDS: hi/lo bf16 tiles as u32 pairs, [64][32] u32, XOR-swizzled (u ^= (row&7)<<2).
// A-frag: row=l&15, k=(l>>4)*8..+7 ; B^T-frag same; C/D: col=l&15, row=(l>>4)*4+i.
template<int D>
__global__ __launch_bounds__(256) void proj_mfma(
    const float* __restrict__ x, const float* __restrict__ w,
    const float* __restrict__ b, float* __restrict__ out)
{
    constexpr int KPAD = (D + 63) & ~63;
    constexpr int NT = KPAD / 64;
    __shared__ u32 Xh[64 * 32], Xl[64 * 32], Wh[64 * 32], Wl[64 * 32];
    const int tid  = threadIdx.x;
    const int base = blockIdx.x * 64;
    const int l  = tid & 63;
    const int wv = tid >> 6;
    const int arow = wv * 16 + (l & 15);
    const int kg = l >> 4;
    f32x4 acc[4] = {};

    for (int t = 0; t < NT; ++t) {
        const int k0 = t * 64;
        for (int i = tid; i < 2048; i += 256) {
            const int row = i >> 5, u = i & 31;
            const int k = k0 + 2 * u;
            const int widx = (row << 5) | (u ^ ((row & 7) << 2));
            // X rows (clamped)
            {
                const int rr = min(base + row, N_NODES - 1);
                float2 v = make_float2(0.f, 0.f);
                if (k + 2 <= D) v = *(const float2*)&x[(size_t)rr * D + k];
                u32 h0, l0, h1, l1;
                bfsplit(v.x, h0, l0); bfsplit(v.y, h1, l1);
                Xh[widx] = h0 | (h1 << 16);
                Xl[widx] = l0 | (l1 << 16);
            }
            // W rows (row = output col)
            {
                float2 v = make_float2(0.f, 0.f);
                if (k + 2 <= D) v = *(const float2*)&w[(size_t)row * D + k];
                u32 h0, l0, h1, l1;
                bfsplit(v.x, h0, l0); bfsplit(v.y, h1, l1);
                Wh[widx] = h0 | (h1 << 16);
                Wl[widx] = l0 | (l1 << 16);
            }
        }
        __syncthreads();
        #pragma unroll
        for (int s = 0; s < 2; ++s) {
            const int ka = (arow << 5) + ((s * 16 + kg * 4) ^ ((arow & 7) << 2));
            const bf16x8 ah = *(const bf16x8*)&Xh[ka];
            const bf16x8 al = *(const bf16x8*)&Xl[ka];
            #pragma unroll
            for (int c = 0; c < 4; ++c) {
                const int brow = c * 16 + (l & 15);
                const int kb = (brow << 5) + ((s * 16 + kg * 4) ^ ((brow & 7) << 2));
                const bf16x8 bh = *(const bf16x8*)&Wh[kb];
                const bf16x8 bl = *(const bf16x8*)&Wl[kb];
                acc[c] = __builtin_amdgcn_mfma_f32_16x16x32_bf16(ah, bh, acc[c], 0, 0, 0);
                acc[c] = __builtin_amdgcn_mfma_f32_16x16x32_bf16(ah, bl, acc[c], 0, 0, 0);
                acc[c] = __builtin_amdgcn_mfma_f32_16x16x32_bf16(al, bh, acc[c], 0, 0, 0);
            }
        }
        __syncthreads();
    }

    const int orow0 = base + wv * 16 + (l >> 4) * 4;
    #pragma unroll
    for (int c = 0; c < 4; ++c) {
        const int col = c * 16 + (l & 15);
        const float bv = b[col];
        #pragma unroll
        for (int i = 0; i < 4; ++i) {
            const int row = orow0 + i;
            if (row < N_NODES)
                out[(size_t)row * H + col] = fmaxf(acc[c][i] + bv, 0.f);
        }
    }
}

// ---------- CSR build: histogram of dst ----------
__global__ __launch_bounds__(256) void hist_dst(
    const int* __restrict__ ei, int* __restrict__ hist)
{
    int e = blockIdx.x * 256 + threadIdx.x;
    if (e < EDGES) atomicAdd(&hist[ei[EDGES + e]], 1);
}

// ---------- device-wide scan, 3 kernels ----------
__global__ __launch_bounds__(256) void scan_partial(
    const int* __restrict__ hist, int* __restrict__ bsum)
{
    __shared__ int red[256];
    const int b = blockIdx.x, t = threadIdx.x;
    const int i0 = b * SCAN_CH + t;
    int s = 0;
    if (i0 < N_NODES) s += hist[i0];
    if (i0 + 256 < N_NODES) s += hist[i0 + 256];
    red[t] = s;
    __syncthreads();
    for (int d = 128; d > 0; d >>= 1) {
        if (t < d) red[t] += red[t + d];
        __syncthreads();
    }
    if (t == 0) bsum[b] = red[0];
}

__global__ __launch_bounds__(256) void scan_tops(
    const int* __restrict__ bsum, int* __restrict__ bpre)
{
    __shared__ int s[256];
    const int t = threadIdx.x;
    const int v = (t < SCAN_BLKS) ? bsum[t] : 0;
    s[t] = v;
    __syncthreads();
    for (int d = 1; d < 256; d <<= 1) {
        int x = (t >= d) ? s[t - d] : 0;
        __syncthreads();
        s[t] += x;
        __syncthreads();
    }
    if (t < SCAN_BLKS) bpre[t] = s[t] - v;
}

__global__ __launch_bounds__(512) void scan_apply(
    const int* __restrict__ hist, const int* __restrict__ bpre,
    int* __restrict__ off, int* __restrict__ cur)
{
    __shared__ int s[512];
    const int b = blockIdx.x, t = threadIdx.x;
    const int i = b * SCAN_CH + t;
    const int h = (i < N_NODES) ? hist[i] : 0;
    s[t] = h;
    __syncthreads();
    for (int d = 1; d < 512; d <<= 1) {
        int x = (t >= d) ? s[t - d] : 0;
        __syncthreads();
        s[t] += x;
        __syncthreads();
    }
    if (i < N_NODES) {
        const int excl = s[t] - h + bpre[b];
        off[i] = excl; cur[i] = excl;
    }
    if (b == 0 && t == 0) off[N_NODES] = EDGES;
}

// ---------- CSR build: fill src lists ----------
__global__ __launch_bounds__(256) void fill_csr(
    const int* __restrict__ ei, int* __restrict__ cur, int* __restrict__ csr)
{
    int e = blockIdx.x * 256 + threadIdx.x;
    if (e < EDGES) {
        int d = ei[EDGES + e];
        int pos = atomicAdd(&cur[d], 1);
        csr[pos] = ei[e];
    }
}

// ---------- gather-reduce: wave per dst node ----------
__global__ __launch_bounds__(256) void gather_mean(
    const float* __restrict__ feat, const int* __restrict__ off,
    const int* __restrict__ csr, float* __restrict__ agg)
{
    const int node = (blockIdx.x * 256 + threadIdx.x) >> 6;
    const int lane = threadIdx.x & 63;
    const int grp  = lane >> 4;
    const int fb   = (lane & 15) * 4;
    const int beg = off[node], end = off[node + 1];
    float4 acc = make_float4(0.f, 0.f, 0.f, 0.f);
    for (int e = beg + grp; e < end; e += 4) {
        int s = csr[e];
        const float4 v = *(const float4*)&feat[(size_t)s * H + fb];
        acc.x += v.x; acc.y += v.y; acc.z += v.z; acc.w += v.w;
    }
    #pragma unroll
    for (int m = 16; m <= 32; m <<= 1) {
        acc.x += __shfl_xor(acc.x, m, 64);
        acc.y += __shfl_xor(acc.y, m, 64);
        acc.z += __shfl_xor(acc.z, m, 64);
        acc.w += __shfl_xor(acc.w, m, 64);
    }
    const float inv = 1.0f / fmaxf((float)(end - beg), 1.0f);
    acc.x *= inv; acc.y *= inv; acc.z *= inv; acc.w *= inv;
    if (grp == 0) *(float4*)&agg[(size_t)node * H + fb] = acc;
}

// ---------- fold conv2+head ----------
__global__ __launch_bounds__(256) void fold_head(
    const float* __restrict__ w_out, const float* __restrict__ wl2,
    const float* __restrict__ wr2, const float* __restrict__ bl2,
    const float* __restrict__ b_out, float* __restrict__ headW)
{
    const int t = threadIdx.x;
    if (t < 128) {
        int o = t >> 6, j = t & 63;
        float s = 0.f;
        for (int h = 0; h < 64; ++h) s += w_out[o * 64 + h] * wl2[h * 64 + j];
        headW[o * 64 + j] = s;
    } else {
        int idx = t - 128, o = idx >> 6, j = idx & 63;
        float s = 0.f;
        for (int h = 0; h < 64; ++h) s += w_out[o * 64 + h] * wr2[h * 64 + j];
        headW[128 + o * 64 + j] = s;
    }
    if (t < 2) {
        float s = b_out[t];
        for (int h = 0; h < 64; ++h) s += w_out[t * 64 + h] * bl2[h];
        headW[256 + t] = s;
    }
}

// ---------- SAGE node update: 64 rows/block, 4x4 reg tiles, 2 K-passes (fp32) ----------
template<bool ZHEAD>
__global__ __launch_bounds__(256) void sage_node(
    const float* __restrict__ agg, const float* __restrict__ xdst,
    const float* __restrict__ wl, const float* __restrict__ bl,
    const float* __restrict__ wr,
    float* __restrict__ out,
    const float* __restrict__ headW, float* __restrict__ z)
{
    __shared__ __align__(16) float At[64 * ST];
    __shared__ __align__(16) float Bt[64 * ST];
    const int tid  = threadIdx.x;
    const int base = blockIdx.x * 64;
    const int col4 = (tid & 15) * 4;
    const int row4 = (tid >> 4) * 4;
    float c[4][4];
    {
        const float4 bv = *(const float4*)&bl[col4];
        #pragma unroll
        for (int i = 0; i < 4; ++i) { c[i][0] = bv.x; c[i][1] = bv.y; c[i][2] = bv.z; c[i][3] = bv.w; }
    }

    #pragma unroll
    for (int pass = 0; pass < 2; ++pass) {
        const float* __restrict__ A = pass ? xdst : agg;
        const float* __restrict__ B = pass ? wr : wl;
        for (int idx = tid; idx < 64 * 64; idx += 256) {
            const int row = idx >> 6, k = idx & 63;
            const int rr = min(base + row, N_NODES - 1);
            At[k * ST + row] = A[(size_t)rr * H + k];
        }
        for (int idx = tid; idx < 64 * 64; idx += 256) {
            const int col = idx >> 6, k = idx & 63;
            Bt[k * ST + col] = B[col * 64 + k];
        }
        __syncthreads();
        #pragma unroll 4
        for (int k = 0; k < 64; ++k) {
            const float4 av = *(const float4*)&At[k * ST + row4];
            const float4 bv = *(const float4*)&Bt[k * ST + col4];
            c[0][0] += av.x * bv.x; c[0][1] += av.x * bv.y; c[0][2] += av.x * bv.z; c[0][3] += av.x * bv.w;
            c[1][0] += av.y * bv.x; c[1][1] += av.y * bv.y; c[1][2] += av.y * bv.z; c[1][3] += av.y * bv.w;
            c[2][0] += av.z * bv.x; c[2][1] += av.z * bv.y; c[2][2] += av.z * bv.z; c[2][3] += av.z * bv.w;
            c[3][0] += av.w * bv.x; c[3][1] += av.w * bv.y; c[3][2] += av.w * bv.z; c[3][3] += av.w * bv.w;
        }
        __syncthreads();
    }

    if (!ZHEAD) {
        #pragma unroll
        for (int i = 0; i < 4; ++i) {
            const int row = base + row4 + i;
            if (row < N_NODES) {
                float4 o;
                o.x = fmaxf(c[i][0], 0.f); o.y = fmaxf(c[i][1], 0.f);
                o.z = fmaxf(c[i][2], 0.f); o.w = fmaxf(c[i][3], 0.f);
                *(float4*)&out[(size_t)row * H + col4] = o;
            }
        }
    } else {
        float* Us = At;
        #pragma unroll
        for (int i = 0; i < 4; ++i)
            #pragma unroll
            for (int jj = 0; jj < 4; ++jj)
                Us[(row4 + i) * 65 + col4 + jj] = fmaxf(c[i][jj], 0.f);
        __syncthreads();
        if (tid < 128) {
            const int r = tid & 63, o = tid >> 6;
            const int row = base + r;
            if (row < N_NODES) {
                float v = 0.f;
                for (int k = 0; k < 64; ++k)
                    v += Us[r * 65 + k] * headW[o * 64 + k];
                z[(size_t)row * 2 + o] = v;
            }
        }
    }
}

// ---------- final: out[n] = mean_p(z) + a1[n] @ Wr'^T + b' ----------
__global__ __launch_bounds__(256) void final_head(
    const int* __restrict__ off, const int* __restrict__ csr,
    const float* __restrict__ z, const float* __restrict__ a1,
    const float* __restrict__ headW, float* __restrict__ out)
{
    const int node = (blockIdx.x * 256 + threadIdx.x) >> 6;
    const int lane = threadIdx.x & 63;
    const int beg = off[node], end = off[node + 1];
    float z0 = 0.f, z1 = 0.f;
    for (int e = beg + lane; e < end; e += 64) {
        int s = csr[e];
        const float2 zv = *(const float2*)&z[(size_t)s * 2];
        z0 += zv.x; z1 += zv.y;
    }
    const float av = a1[(size_t)node * H + lane];
    float p0 = av * headW[128 + lane];
    float p1 = av * headW[192 + lane];
    #pragma unroll
    for (int m = 1; m <= 32; m <<= 1) {
        z0 += __shfl_xor(z0, m, 64);
        z1 += __shfl_xor(z1, m, 64);
        p0 += __shfl_xor(p0, m, 64);
        p1 += __shfl_xor(p1, m, 64);
    }
    if (lane == 0) {
        const float inv = 1.0f / fmaxf((float)(end - beg), 1.0f);
        float2 o;
        o.x = z0 * inv + p0 + headW[256];
        o.y = z1 * inv + p1 + headW[257];
        *(float2*)&out[(size_t)node * 2] = o;
    }
}

extern "C" void kernel_launch(void* const* d_in, const int* in_sizes, int n_in,
                              void* d_out, int out_size, void* d_ws, size_t ws_size,
                              hipStream_t stream) {
    const float* x_a    = (const float*)d_in[0];
    const float* x_u    = (const float*)d_in[1];
    const int*   ei_p   = (const int*)d_in[2];
    const int*   ei_b   = (const int*)d_in[3];
    const float* w_in_a = (const float*)d_in[4];
    const float* b_in_a = (const float*)d_in[5];
    const float* w_in_u = (const float*)d_in[6];
    const float* b_in_u = (const float*)d_in[7];
    const float* c1p_wl = (const float*)d_in[8];
    const float* c1p_bl = (const float*)d_in[9];
    const float* c1p_wr = (const float*)d_in[10];
    const float* c1b_wl = (const float*)d_in[11];
    const float* c1b_bl = (const float*)d_in[12];
    const float* c1b_wr = (const float*)d_in[13];
    const float* c2p_wl = (const float*)d_in[14];
    const float* c2p_bl = (const float*)d_in[15];
    const float* c2p_wr = (const float*)d_in[16];
    const float* w_out  = (const float*)d_in[20];
    const float* b_out  = (const float*)d_in[21];

    const size_t NF = (size_t)N_NODES * H;
    float* bufA  = (float*)d_ws;
    float* bufU  = bufA + NF;
    float* agg   = bufU + NF;
    float* z     = agg + NF;
    float* headW = z + 2 * N_NODES;
    int* off_p  = (int*)(headW + 512);
    int* off_b  = off_p + OFFPAD;
    int* cur_p  = off_b + OFFPAD;
    int* cur_b  = cur_p + OFFPAD;
    int* hist_p = cur_b + OFFPAD;
    int* hist_b = hist_p + OFFPAD;
    int* bsum_p = hist_b + OFFPAD;
    int* bsum_b = bsum_p + 256;
    int* bpre_p = bsum_b + 256;
    int* bpre_b = bpre_p + 256;
    int* csr_p  = bpre_b + 256;
    int* csr_b  = csr_p + EDGES;

    const dim3 blk(256);
    const int grid_edge = EDGES / 256;
    const int grid_gemm = (N_NODES + 63) / 64;   // 1563
    const int grid_wave = N_NODES / 4;           // 25000

    // --- CSR build ---
    hipMemsetAsync(hist_p, 0, 2 * OFFPAD * sizeof(int), stream);
    hist_dst<<<grid_edge, blk, 0, stream>>>(ei_p, hist_p);
    hist_dst<<<grid_edge, blk, 0, stream>>>(ei_b, hist_b);
    scan_partial<<<SCAN_BLKS, blk, 0, stream>>>(hist_p, bsum_p);
    scan_partial<<<SCAN_BLKS, blk, 0, stream>>>(hist_b, bsum_b);
    scan_tops<<<1, blk, 0, stream>>>(bsum_p, bpre_p);
    scan_tops<<<1, blk, 0, stream>>>(bsum_b, bpre_b);
    scan_apply<<<SCAN_BLKS, 512, 0, stream>>>(hist_p, bpre_p, off_p, cur_p);
    scan_apply<<<SCAN_BLKS, 512, 0, stream>>>(hist_b, bpre_b, off_b, cur_b);
    fill_csr<<<grid_edge, blk, 0, stream>>>(ei_p, cur_p, csr_p);
    fill_csr<<<grid_edge, blk, 0, stream>>>(ei_b, cur_b, csr_b);

    // --- input projections (MFMA, bf16-split) ---
    proj_mfma<300><<<grid_gemm, blk, 0, stream>>>(x_a, w_in_a, b_in_a, bufA);
    proj_mfma<64> <<<grid_gemm, blk, 0, stream>>>(x_u, w_in_u, b_in_u, bufU);

    fold_head<<<1, blk, 0, stream>>>(w_out, c2p_wl, c2p_wr, c2p_bl, b_out, headW);

    // user side: agg articles (ei_pb), z = relu(sage)@Wl'^T (u1 never stored)
    gather_mean<<<grid_wave, blk, 0, stream>>>(bufA, off_b, csr_b, agg);
    sage_node<true><<<grid_gemm, blk, 0, stream>>>(
        agg, bufU, c1b_wl, c1b_bl, c1b_wr, nullptr, headW, z);

    // article side: agg users (ei_posts), a1 in-place over bufA
    gather_mean<<<grid_wave, blk, 0, stream>>>(bufU, off_p, csr_p, agg);
    sage_node<false><<<grid_gemm, blk, 0, stream>>>(
        agg, bufA, c1p_wl, c1p_bl, c1p_wr, bufA, nullptr, nullptr);

    final_head<<<grid_wave, blk, 0, stream>>>(off_p, csr_p, z, bufA, headW, (float*)d_out);

    (void)in_sizes; (void)n_in; (void)out_size; (void)ws_size;
}